// Round 10
// baseline (1747.714 us; speedup 1.0000x reference)
//
#include <hip/hip_runtime.h>
#include <stdint.h>

#define DEV __device__ __forceinline__

typedef __attribute__((ext_vector_type(8))) short short8;
typedef __attribute__((ext_vector_type(4))) float f32x4;
typedef __attribute__((ext_vector_type(4))) short short4v;

static constexpr int BATCH = 2, SEQ = 2048, DM = 1024, NH = 16, NKV = 8, HD = 64;
static constexpr int NTOK = BATCH * SEQ;   // 4096
static constexpr int NE = 8, FF = 3584;

DEV unsigned short f2bf(float f) {
  union { float f; unsigned u; } x; x.f = f;
  unsigned r = x.u + 0x7fffu + ((x.u >> 16) & 1u);
  return (unsigned short)(r >> 16);
}
DEV float bf2f(unsigned short h) {
  union { unsigned u; float f; } x; x.u = ((unsigned)h) << 16; return x.f;
}

DEV void async16(const void* g, void* l) {
  __builtin_amdgcn_global_load_lds((const __attribute__((address_space(1))) unsigned int*)g,
                                   (__attribute__((address_space(3))) unsigned int*)l, 16, 0, 0);
}

DEV f32x4 mfma16(short8 a, short8 b, f32x4 c) {
  return __builtin_amdgcn_mfma_f32_16x16x32_bf16(a, b, c, 0, 0, 0);
}

// ---------------- transpose + fp32->bf16 convert (vectorized):  out[c][r] = bf16(in[r][c])
__global__ __launch_bounds__(256) void transpose_cvt_k(
    const float* __restrict__ in, unsigned short* __restrict__ out,
    int R, int C, long inStride, long outStride)
{
  __shared__ unsigned short tile[64][68];
  const float* src = in + (long)blockIdx.z * inStride;
  unsigned short* dst = out + (long)blockIdx.z * outStride;
  int r0 = blockIdx.y * 64, c0 = blockIdx.x * 64;
  int s4 = (threadIdx.x & 15) * 4, rr = threadIdx.x >> 4;   // 16 slots x 16 rows
#pragma unroll
  for (int i = 0; i < 4; ++i) {
    int r = rr + i * 16;
    float4 v = *(const float4*)(src + (long)(r0 + r) * C + c0 + s4);
    tile[r][s4 + 0] = f2bf(v.x); tile[r][s4 + 1] = f2bf(v.y);
    tile[r][s4 + 2] = f2bf(v.z); tile[r][s4 + 3] = f2bf(v.w);
  }
  __syncthreads();
#pragma unroll
  for (int i = 0; i < 4; ++i) {
    int c = rr + i * 16;
    union { unsigned short us[4]; short4v v; } o;
    o.us[0] = tile[s4 + 0][c]; o.us[1] = tile[s4 + 1][c];
    o.us[2] = tile[s4 + 2][c]; o.us[3] = tile[s4 + 3][c];
    *(short4v*)(dst + (long)(c0 + c) * R + r0 + s4) = o.v;
  }
}

// ---------------- rmsnorm (fp32 in, bf16 out) ----------------
__global__ __launch_bounds__(256) void rmsnorm_k(
    const float* __restrict__ x, const float* __restrict__ w, unsigned short* __restrict__ out)
{
  int row = blockIdx.x, t = threadIdx.x;
  const float4* xr = (const float4*)(x + (long)row * DM);
  float4 v = xr[t];
  float ss = v.x * v.x + v.y * v.y + v.z * v.z + v.w * v.w;
#pragma unroll
  for (int o = 32; o; o >>= 1) ss += __shfl_xor(ss, o);
  __shared__ float red[4];
  if ((t & 63) == 0) red[t >> 6] = ss;
  __syncthreads();
  float tot = red[0] + red[1] + red[2] + red[3];
  float rms = rsqrtf(tot * (1.0f / DM) + 1e-5f);
  float4 wv = ((const float4*)w)[t];
  union { unsigned short us[4]; short4v s; } o4;
  o4.us[0] = f2bf(v.x * rms * wv.x);
  o4.us[1] = f2bf(v.y * rms * wv.y);
  o4.us[2] = f2bf(v.z * rms * wv.z);
  o4.us[3] = f2bf(v.w * rms * wv.w);
  *(short4v*)(out + (long)row * DM + 4 * t) = o4.s;
}

// ---------------- dense 128x128 MFMA GEMM: C = A[M,K] * Bt[N,K]^T ----------------
// MODE 0: bf16 C out.  MODE 1: fp32 out = resid + acc.
template<int MODE>
__global__ __launch_bounds__(256) void gemm_k(
    const unsigned short* __restrict__ A, const unsigned short* __restrict__ B0,
    void* __restrict__ Cout, const float* __restrict__ resid,
    int M, int N, int K, int ldA, int ldB, int ldC)
{
  constexpr int BM = 128, BN = 128, BK = 64;
  __shared__ __align__(16) unsigned short As[BM * BK];
  __shared__ __align__(16) unsigned short Bs[BN * BK];
  int bm = blockIdx.x, bn = blockIdx.y;
  int t = threadIdx.x, w = t >> 6, l = t & 63, g = l >> 4, q = l & 15;
  int wm = w >> 1, wn = w & 1;

  const char* aSrc[4];
  const char* bSrc[4];
#pragma unroll
  for (int i = 0; i < 4; ++i) {
    int r = i * 32 + w * 8 + (l >> 3);
    aSrc[i] = (const char*)(A + (long)(bm * BM + r) * ldA) + (((l & 7) * 16) ^ ((r & 7) << 4));
    bSrc[i] = (const char*)(B0 + (long)(bn * BN + r) * ldB) + (((l & 7) * 16) ^ ((r & 7) << 4));
  }
  f32x4 acc[4][4];
#pragma unroll
  for (int mi = 0; mi < 4; ++mi)
#pragma unroll
    for (int ni = 0; ni < 4; ++ni) acc[mi][ni] = f32x4{0.f, 0.f, 0.f, 0.f};

  for (int k0 = 0; k0 < K; k0 += BK) {
#pragma unroll
    for (int i = 0; i < 4; ++i) {
      async16(aSrc[i] + (long)k0 * 2, &As[(i * 32 + w * 8) * BK]);
      async16(bSrc[i] + (long)k0 * 2, &Bs[(i * 32 + w * 8) * BK]);
    }
    asm volatile("s_waitcnt vmcnt(0)" ::: "memory");
    __syncthreads();
#pragma unroll
    for (int kk = 0; kk < 2; ++kk) {
      int col = (kk * 64 + g * 16) ^ ((q & 7) << 4);
      short8 af[4], bfm[4];
#pragma unroll
      for (int mi = 0; mi < 4; ++mi)
        af[mi] = *(const short8*)&As[(wm * 64 + mi * 16 + q) * BK + (col >> 1)];
#pragma unroll
      for (int ni = 0; ni < 4; ++ni)
        bfm[ni] = *(const short8*)&Bs[(wn * 64 + ni * 16 + q) * BK + (col >> 1)];
#pragma unroll
      for (int mi = 0; mi < 4; ++mi)
#pragma unroll
        for (int ni = 0; ni < 4; ++ni)
          acc[mi][ni] = mfma16(af[mi], bfm[ni], acc[mi][ni]);
    }
    __syncthreads();
  }
#pragma unroll
  for (int mi = 0; mi < 4; ++mi) {
#pragma unroll
    for (int r = 0; r < 4; ++r) {
      int grow = bm * BM + wm * 64 + mi * 16 + g * 4 + r;
#pragma unroll
      for (int ni = 0; ni < 4; ++ni) {
        int gcol = bn * BN + wn * 64 + ni * 16 + q;
        float v = acc[mi][ni][r];
        if (MODE == 0) {
          ((unsigned short*)Cout)[(long)grow * ldC + gcol] = f2bf(v);
        } else {
          long idx = (long)grow * ldC + gcol;
          ((float*)Cout)[idx] = resid[idx] + v;
        }
      }
    }
  }
}

// ------- persistent fused MoE up-proj: BM=256, 512 thr (8 waves = 4Mx2N), BN=64 dual-B.
//         h = silu(x@w1)*(x@w3) -> hbuf, gathered A rows.  tb-outer/jj-inner for L2 reuse.
__global__ __launch_bounds__(512, 6) void moe_up_k(
    const unsigned short* __restrict__ xn, const unsigned short* __restrict__ w1T,
    const unsigned short* __restrict__ w3T, unsigned short* __restrict__ hbuf,
    const int* __restrict__ lstAll, const int* __restrict__ cntAll)
{
  constexpr int BM = 256, BN = 64, BK = 64, NBN = FF / BN;   // 56
  constexpr int NJJ = NBN / 8;                                // 7 bn-tiles per XCD
  __shared__ __align__(16) unsigned short As[BM * BK];        // 32 KB
  __shared__ __align__(16) unsigned short Bs[2][BN * BK];     // 16 KB
  int t = threadIdx.x, w = t >> 6, l = t & 63, g = l >> 4, q = l & 15;
  int wm = w >> 1, wn = w & 1;                                // wm 0..3, wn 0..1
  int xcd = blockIdx.x & 7, slot = blockIdx.x >> 3, SLOTS = gridDim.x >> 3;

  int TB = 0;
  for (int e = 0; e < NE; ++e) TB += (cntAll[e] + BM - 1) >> 8;

  for (int lidx = slot; lidx < TB * NJJ; lidx += SLOTS) {
    int tb = lidx / NJJ, jj = lidx - tb * NJJ;
    int bn = xcd + 8 * jj;
    int e = 0, base = 0, cnt = 0, bm = 0;
    for (; e < NE; ++e) {
      cnt = cntAll[e];
      int te = (cnt + BM - 1) >> 8;
      if (tb < te) { bm = tb; break; }
      tb -= te; base += cnt;
    }
    const int* lst = lstAll + e * NTOK;
    const unsigned short* B0 = w1T + (size_t)e * FF * DM + (size_t)bn * BN * DM;
    const unsigned short* B1 = w3T + (size_t)e * FF * DM + (size_t)bn * BN * DM;

    const char* aSrc[4];
    const char* b0Src;
    const char* b1Src;
#pragma unroll
    for (int i = 0; i < 4; ++i) {
      int r = i * 64 + w * 8 + (l >> 3);
      int grow = bm * BM + r;
      int arow = lst[grow < cnt ? grow : 0];
      int swz = ((l & 7) * 16) ^ ((r & 7) << 4);
      aSrc[i] = (const char*)(xn + (long)arow * DM) + swz;
    }
    {
      int r = w * 8 + (l >> 3);
      int swz = ((l & 7) * 16) ^ ((r & 7) << 4);
      b0Src = (const char*)(B0 + (long)r * DM) + swz;
      b1Src = (const char*)(B1 + (long)r * DM) + swz;
    }
    f32x4 acc0[4][2], acc1[4][2];
#pragma unroll
    for (int mi = 0; mi < 4; ++mi)
#pragma unroll
      for (int ni = 0; ni < 2; ++ni) {
        acc0[mi][ni] = f32x4{0.f, 0.f, 0.f, 0.f};
        acc1[mi][ni] = f32x4{0.f, 0.f, 0.f, 0.f};
      }

    for (int k0 = 0; k0 < DM; k0 += BK) {
#pragma unroll
      for (int i = 0; i < 4; ++i)
        async16(aSrc[i] + (long)k0 * 2, &As[(i * 64 + w * 8) * BK]);
      async16(b0Src + (long)k0 * 2, &Bs[0][(w * 8) * BK]);
      async16(b1Src + (long)k0 * 2, &Bs[1][(w * 8) * BK]);
      asm volatile("s_waitcnt vmcnt(0)" ::: "memory");
      __syncthreads();
#pragma unroll
      for (int kk = 0; kk < 2; ++kk) {
        int col = (kk * 64 + g * 16) ^ ((q & 7) << 4);
        short8 af[4], bf0[2], bf1[2];
#pragma unroll
        for (int mi = 0; mi < 4; ++mi)
          af[mi] = *(const short8*)&As[(wm * 64 + mi * 16 + q) * BK + (col >> 1)];
#pragma unroll
        for (int ni = 0; ni < 2; ++ni) {
          int r = wn * 32 + ni * 16 + q;
          bf0[ni] = *(const short8*)&Bs[0][r * BK + (col >> 1)];
          bf1[ni] = *(const short8*)&Bs[1][r * BK + (col >> 1)];
        }
#pragma unroll
        for (int mi = 0; mi < 4; ++mi)
#pragma unroll
          for (int ni = 0; ni < 2; ++ni) {
            acc0[mi][ni] = mfma16(af[mi], bf0[ni], acc0[mi][ni]);
            acc1[mi][ni] = mfma16(af[mi], bf1[ni], acc1[mi][ni]);
          }
      }
      __syncthreads();
    }
#pragma unroll
    for (int mi = 0; mi < 4; ++mi) {
#pragma unroll
      for (int r = 0; r < 4; ++r) {
        int grow = bm * BM + wm * 64 + mi * 16 + g * 4 + r;
        if (grow >= cnt) continue;
        unsigned short* hp = hbuf + (size_t)(base + grow) * FF + bn * BN + wn * 32;
#pragma unroll
        for (int ni = 0; ni < 2; ++ni) {
          float v1 = acc0[mi][ni][r];
          float v3 = acc1[mi][ni][r];
          float sg = v1 / (1.0f + __expf(-v1));
          hp[ni * 16 + q] = f2bf(sg * v3);
        }
      }
    }
  }
}

// ------- persistent MoE down-proj (bn==XCD, BN=128, single-buffer m97 schedule):
//         y = h @ w2 -> ybuf slot-major.
__global__ __launch_bounds__(256, 3) void moe_dn_k(
    const unsigned short* __restrict__ hbuf, const unsigned short* __restrict__ w2T,
    unsigned short* __restrict__ ybuf, const int* __restrict__ cntAll)
{
  constexpr int BM = 128, BN = 128, BK = 64;                 // DM/BN == 8 == NXCD
  __shared__ __align__(16) unsigned short As[BM * BK];
  __shared__ __align__(16) unsigned short Bs[BN * BK];
  int t = threadIdx.x, w = t >> 6, l = t & 63, g = l >> 4, q = l & 15;
  int wm = w >> 1, wn = w & 1;
  int xcd = blockIdx.x & 7, slot = blockIdx.x >> 3, SLOTS = gridDim.x >> 3;
  int bn = xcd;

  int TB = 0;
  for (int e = 0; e < NE; ++e) TB += (cntAll[e] + BM - 1) >> 7;

  for (int tb0 = slot; tb0 < TB; tb0 += SLOTS) {
    int tb = tb0;
    int e = 0, base = 0, cnt = 0, bm = 0;
    for (; e < NE; ++e) {
      cnt = cntAll[e];
      int te = (cnt + BM - 1) >> 7;
      if (tb < te) { bm = tb; break; }
      tb -= te; base += cnt;
    }
    const unsigned short* B0 = w2T + (size_t)e * DM * FF + (size_t)bn * BN * FF;

    const char* aSrc[4];
    const char* bSrc[4];
#pragma unroll
    for (int i = 0; i < 4; ++i) {
      int r = i * 32 + w * 8 + (l >> 3);
      int grow = bm * BM + r;
      int arow = base + (grow < cnt ? grow : 0);
      int swz = ((l & 7) * 16) ^ ((r & 7) << 4);
      aSrc[i] = (const char*)(hbuf + (long)arow * FF) + swz;
      bSrc[i] = (const char*)(B0 + (long)r * FF) + swz;
    }
    f32x4 acc[4][4];
#pragma unroll
    for (int mi = 0; mi < 4; ++mi)
#pragma unroll
      for (int ni = 0; ni < 4; ++ni) acc[mi][ni] = f32x4{0.f, 0.f, 0.f, 0.f};

    for (int k0 = 0; k0 < FF; k0 += BK) {
#pragma unroll
      for (int i = 0; i < 4; ++i) {
        async16(aSrc[i] + (long)k0 * 2, &As[(i * 32 + w * 8) * BK]);
        async16(bSrc[i] + (long)k0 * 2, &Bs[(i * 32 + w * 8) * BK]);
      }
      asm volatile("s_waitcnt vmcnt(0)" ::: "memory");
      __syncthreads();
#pragma unroll
      for (int kk = 0; kk < 2; ++kk) {
        int col = (kk * 64 + g * 16) ^ ((q & 7) << 4);
        short8 af[4], bfm[4];
#pragma unroll
        for (int mi = 0; mi < 4; ++mi)
          af[mi] = *(const short8*)&As[(wm * 64 + mi * 16 + q) * BK + (col >> 1)];
#pragma unroll
        for (int ni = 0; ni < 4; ++ni)
          bfm[ni] = *(const short8*)&Bs[(wn * 64 + ni * 16 + q) * BK + (col >> 1)];
#pragma unroll
        for (int mi = 0; mi < 4; ++mi)
#pragma unroll
          for (int ni = 0; ni < 4; ++ni)
            acc[mi][ni] = mfma16(af[mi], bfm[ni], acc[mi][ni]);
      }
      __syncthreads();
    }
#pragma unroll
    for (int mi = 0; mi < 4; ++mi) {
#pragma unroll
      for (int r = 0; r < 4; ++r) {
        int grow = bm * BM + wm * 64 + mi * 16 + g * 4 + r;
        if (grow >= cnt) continue;
        unsigned short* yp = ybuf + (size_t)(base + grow) * DM + bn * BN + wn * 64;
#pragma unroll
        for (int ni = 0; ni < 4; ++ni)
          yp[ni * 16 + q] = f2bf(acc[mi][ni][r]);
      }
    }
  }
}

// ---------------- final MoE gather: out[tok] += w0*y[slot0] + w1*y[slot1] --------------
__global__ __launch_bounds__(256) void moe_gather_k(
    const unsigned short* __restrict__ ybuf, const int* __restrict__ tokslot,
    const float* __restrict__ wtop, const int* __restrict__ cntAll,
    float* __restrict__ out)
{
  __shared__ int base8[NE];
  int tok = blockIdx.x, t = threadIdx.x;
  if (t < NE) {
    int b = 0;
    for (int i = 0; i < t; ++i) b += cntAll[i];
    base8[t] = b;
  }
  __syncthreads();
  int s0 = tokslot[2 * tok], s1 = tokslot[2 * tok + 1];
  int slot0 = base8[s0 >> 16] + (s0 & 0xffff);
  int slot1 = base8[s1 >> 16] + (s1 & 0xffff);
  float w0 = wtop[2 * tok], w1 = wtop[2 * tok + 1];
  short4v a = *(const short4v*)(ybuf + (size_t)slot0 * DM + 4 * t);
  short4v b = *(const short4v*)(ybuf + (size_t)slot1 * DM + 4 * t);
  float4* op = (float4*)(out + (size_t)tok * DM);
  float4 o = op[t];
  o.x += w0 * bf2f((unsigned short)a[0]) + w1 * bf2f((unsigned short)b[0]);
  o.y += w0 * bf2f((unsigned short)a[1]) + w1 * bf2f((unsigned short)b[1]);
  o.z += w0 * bf2f((unsigned short)a[2]) + w1 * bf2f((unsigned short)b[2]);
  o.w += w0 * bf2f((unsigned short)a[3]) + w1 * bf2f((unsigned short)b[3]);
  op[t] = o;
}

// ---------------- RoPE (in-place on qkv bf16 buffer) ----------------
__global__ __launch_bounds__(256) void rope_k(unsigned short* __restrict__ qkv,
                                              const int* __restrict__ pos)
{
  int tok = blockIdx.x, t = threadIdx.x;
  __shared__ float cs[32], sn[32];
  if (t < 32) {
    float p = (float)pos[tok];
    float freq = __expf(-(float)t * 0.28782313663f);  // ln(10000)/32
    float a = p * freq;
    cs[t] = cosf(a); sn[t] = sinf(a);
  }
  __syncthreads();
  unsigned short* row = qkv + (long)tok * 2048;
#pragma unroll
  for (int idx = t; idx < 768; idx += 256) {
    int hh = idx >> 5, d = idx & 31;
    int col = (hh < 16) ? hh * 64 + d : 1024 + (hh - 16) * 64 + d;
    float x1 = bf2f(row[col]), x2 = bf2f(row[col + 32]);
    row[col]      = f2bf(x1 * cs[d] - x2 * sn[d]);
    row[col + 32] = f2bf(x2 * cs[d] + x1 * sn[d]);
  }
}

// ---------------- V transpose: qkv V-section -> VtG[b][kvh][d=64][S] ----------------
__global__ __launch_bounds__(256) void vtrans_k(const unsigned short* __restrict__ qkv,
                                                unsigned short* __restrict__ vt)
{
  __shared__ unsigned short tile[64][72];
  int s0 = blockIdx.x * 64, kvh = blockIdx.y, b = blockIdx.z;
  int t = threadIdx.x;
  int tx4 = (t & 15) * 4, row = t >> 4;
  const unsigned short* src = qkv + (long)(b * SEQ + s0) * 2048 + 1536 + kvh * 64;
#pragma unroll
  for (int i = 0; i < 4; ++i) {
    int r = row + i * 16;
    *(short4v*)&tile[r][tx4] = *(const short4v*)(src + (long)r * 2048 + tx4);
  }
  __syncthreads();
  unsigned short* dst = vt + (long)((b * NKV + kvh) * 64) * SEQ + s0;
#pragma unroll
  for (int i = 0; i < 4; ++i) {
    int d = row + i * 16;
    union { unsigned short us[4]; short4v v; } o;
    o.us[0] = tile[tx4 + 0][d]; o.us[1] = tile[tx4 + 1][d];
    o.us[2] = tile[tx4 + 2][d]; o.us[3] = tile[tx4 + 3][d];
    *(short4v*)(dst + (long)d * SEQ + tx4) = o.v;
  }
}

// ---------------- causal GQA flash attention (512 thr: 2 heads of one KV group) --------
__global__ __launch_bounds__(512) void attn_k(const unsigned short* __restrict__ qkv,
                                              const unsigned short* __restrict__ vtg,
                                              unsigned short* __restrict__ aout)
{
  int b = blockIdx.z;
  int qt = b ? (31 - blockIdx.x) : blockIdx.x;
  int kvh = blockIdx.y;
  int t = threadIdx.x, w = t >> 6, l = t & 63, g = l >> 4, q = l & 15;
  int h = kvh * 2 + (w >> 2);
  int wl = w & 3;
  __shared__ __align__(16) unsigned short Ks[2][4096];
  __shared__ __align__(16) unsigned short Vs[2][4096];
  int tok0 = b * SEQ;
  int myq = qt * 64 + wl * 16 + q;
  const unsigned short* qp = qkv + (long)(tok0 + myq) * 2048 + h * 64;
  short8 qf0 = *(const short8*)(qp + g * 8);
  short8 qf1 = *(const short8*)(qp + 32 + g * 8);
  const unsigned short* vtb = vtg + (long)((b * NKV + kvh) * 64) * SEQ;
  f32x4 o[4];
#pragma unroll
  for (int nf = 0; nf < 4; ++nf) o[nf] = f32x4{0.f, 0.f, 0.f, 0.f};
  float m = -1e30f, ssum = 0.0f;
  int r8 = w * 8 + (l >> 3);
  int sswz = ((l & 7) * 16) ^ ((r8 & 7) << 4);

  auto stage = [&](int kt, int buf) {
    const char* ksrc = (const char*)(qkv + (long)(tok0 + kt * 64 + r8) * 2048 + 1024 + kvh * 64) + sswz;
    async16(ksrc, &Ks[buf][r8 * 64]);
    const char* vsrc = (const char*)(vtb + (long)r8 * SEQ + kt * 64) + sswz;
    async16(vsrc, &Vs[buf][r8 * 64]);
  };

  stage(0, 0);
  __syncthreads();
  int cur = 0;
  for (int kt = 0; kt <= qt; ++kt) {
    if (kt < qt) stage(kt + 1, cur ^ 1);
    f32x4 st[4];
#pragma unroll
    for (int mb = 0; mb < 4; ++mb) {
      int kr = mb * 16 + q;
      int c0 = (g * 16) ^ ((q & 7) << 4);
      int c1 = (64 + g * 16) ^ ((q & 7) << 4);
      short8 k0 = *(const short8*)&Ks[cur][kr * 64 + (c0 >> 1)];
      short8 k1 = *(const short8*)&Ks[cur][kr * 64 + (c1 >> 1)];
      f32x4 z = f32x4{0.f, 0.f, 0.f, 0.f};
      __builtin_amdgcn_s_setprio(1);
      z = mfma16(k0, qf0, z);
      z = mfma16(k1, qf1, z);
      __builtin_amdgcn_s_setprio(0);
      st[mb] = z;
    }
    float p[4][4];
    float tmax = -1e30f;
#pragma unroll
    for (int mb = 0; mb < 4; ++mb)
#pragma unroll
      for (int r = 0; r < 4; ++r) {
        float v = st[mb][r] * 0.125f;
        int kvg = kt * 64 + mb * 16 + g * 4 + r;
        if (kvg > myq) v = -1e30f;
        p[mb][r] = v;
        tmax = fmaxf(tmax, v);
      }
    tmax = fmaxf(tmax, __shfl_xor(tmax, 16));
    tmax = fmaxf(tmax, __shfl_xor(tmax, 32));
    float mnew = fmaxf(m, tmax);
    float fac = __expf(m - mnew);
    m = mnew;
    float ps = 0.0f;
#pragma unroll
    for (int mb = 0; mb < 4; ++mb)
#pragma unroll
      for (int r = 0; r < 4; ++r) { float e = __expf(p[mb][r] - m); p[mb][r] = e; ps += e; }
    ps += __shfl_xor(ps, 16);
    ps += __shfl_xor(ps, 32);
    ssum = ssum * fac + ps;
#pragma unroll
    for (int r = 0; r < 4; ++r) {
      float ff = __shfl(fac, g * 4 + r);
#pragma unroll
      for (int nf = 0; nf < 4; ++nf) o[nf][r] *= ff;
    }
    unsigned pw[4][2];
#pragma unroll
    for (int mb = 0; mb < 4; ++mb) {
      pw[mb][0] = ((unsigned)f2bf(p[mb][1]) << 16) | f2bf(p[mb][0]);
      pw[mb][1] = ((unsigned)f2bf(p[mb][3]) << 16) | f2bf(p[mb][2]);
    }
    short8 pa[2];
#pragma unroll
    for (int f = 0; f < 2; ++f) {
      union { unsigned u[4]; short8 s; } cv;
#pragma unroll
      for (int i = 0; i < 4; ++i) {
        int srcl = ((g & 1) * 2 + (i >> 1)) * 16 + q;
        unsigned aa = (unsigned)__shfl((int)pw[2 * f][i & 1], srcl);
        unsigned bb = (unsigned)__shfl((int)pw[2 * f + 1][i & 1], srcl);
        cv.u[i] = (g & 2) ? bb : aa;
      }
      pa[f] = cv.s;
    }
#pragma unroll
    for (int kk = 0; kk < 2; ++kk) {
      int cb = (kk * 64 + g * 16) ^ ((q & 7) << 4);
      __builtin_amdgcn_s_setprio(1);
#pragma unroll
      for (int nf = 0; nf < 4; ++nf) {
        short8 vb = *(const short8*)&Vs[cur][(nf * 16 + q) * 64 + (cb >> 1)];
        o[nf] = mfma16(pa[kk], vb, o[nf]);
      }
      __builtin_amdgcn_s_setprio(0);
    }
    __syncthreads();
    cur ^= 1;
  }
#pragma unroll
  for (int r = 0; r < 4; ++r) {
    float is = 1.0f / __shfl(ssum, g * 4 + r);
    int orow = tok0 + qt * 64 + wl * 16 + g * 4 + r;
    unsigned short* op = aout + (long)orow * 1024 + h * 64;
    op[q]      = f2bf(o[0][r] * is);
    op[16 + q] = f2bf(o[1][r] * is);
    op[32 + q] = f2bf(o[2][r] * is);
    op[48 + q] = f2bf(o[3][r] * is);
  }
}

// ---------------- rmsnorm2 + router (atomic-free: per-token writes only) ----------------
__global__ __launch_bounds__(256) void router_k(
    const float* __restrict__ hid, const float* __restrict__ w2n, const float* __restrict__ Wg,
    unsigned short* __restrict__ xn, float* __restrict__ probs8,
    int* __restrict__ top0, int* __restrict__ top1, float* __restrict__ wtop)
{
  int row = blockIdx.x, t = threadIdx.x;
  const float4* xr = (const float4*)(hid + (long)row * DM);
  float4 v = xr[t];
  float ss = v.x * v.x + v.y * v.y + v.z * v.z + v.w * v.w;
#pragma unroll
  for (int o = 32; o; o >>= 1) ss += __shfl_xor(ss, o);
  __shared__ float red[4];
  __shared__ float lred[4][8];
  __shared__ float lg[8];
  if ((t & 63) == 0) red[t >> 6] = ss;
  __syncthreads();
  float tot = red[0] + red[1] + red[2] + red[3];
  float rms = rsqrtf(tot * (1.0f / DM) + 1e-5f);
  float4 wv = ((const float4*)w2n)[t];
  float x0 = v.x * rms * wv.x, x1 = v.y * rms * wv.y, x2 = v.z * rms * wv.z, x3 = v.w * rms * wv.w;
  union { unsigned short us[4]; short4v s; } o4;
  o4.us[0] = f2bf(x0); o4.us[1] = f2bf(x1); o4.us[2] = f2bf(x2); o4.us[3] = f2bf(x3);
  *(short4v*)(xn + (long)row * DM + 4 * t) = o4.s;
  const float* wgr = Wg + t * 32;
  float lacc[8];
#pragma unroll
  for (int e = 0; e < 8; ++e)
    lacc[e] = x0 * wgr[e] + x1 * wgr[8 + e] + x2 * wgr[16 + e] + x3 * wgr[24 + e];
#pragma unroll
  for (int e = 0; e < 8; ++e)
#pragma unroll
    for (int o = 32; o; o >>= 1) lacc[e] += __shfl_xor(lacc[e], o);
  if ((t & 63) == 0)
#pragma unroll
    for (int e = 0; e < 8; ++e) lred[t >> 6][e] = lacc[e];
  __syncthreads();
  if (t < 8) lg[t] = lred[0][t] + lred[1][t] + lred[2][t] + lred[3][t];
  __syncthreads();
  if (t == 0) {
    float p[8];
    float mx = lg[0];
#pragma unroll
    for (int e = 1; e < 8; ++e) mx = fmaxf(mx, lg[e]);
    float s = 0.f;
#pragma unroll
    for (int e = 0; e < 8; ++e) { p[e] = __expf(lg[e] - mx); s += p[e]; }
    float isv = 1.0f / s;
#pragma unroll
    for (int e = 0; e < 8; ++e) { p[e] *= isv; probs8[(long)row * 8 + e] = p[e]; }
    int i0 = 0;
#pragma unroll
    for (int e = 1; e < 8; ++e) if (p[e] > p[i0]) i0 = e;
    int i1 = (i0 == 0) ? 1 : 0;
#pragma unroll
    for (int e = 0; e < 8; ++e) if (e != i0 && p[e] > p[i1]) i1 = e;
    float sw = p[i0] + p[i1];
    top0[row] = i0; top1[row] = i1;
    wtop[2 * row] = p[i0] / sw; wtop[2 * row + 1] = p[i1] / sw;
  }
}

// ---------------- expert list compaction (deterministic, no atomics) ----------------
__global__ __launch_bounds__(256) void build_lists_k(
    const int* __restrict__ top0, const int* __restrict__ top1,
    const float* __restrict__ wtop, int* __restrict__ lst, int* __restrict__ tokslot,
    int* __restrict__ ecnt, int* __restrict__ cnt0, int* __restrict__ cnt1)
{
  int e = blockIdx.x, t = threadIdx.x, lane = t & 63, wv = t >> 6;
  __shared__ int wco[4];
  int base = 0, c0 = 0, c1 = 0;
  for (int t0 = 0; t0 < NTOK; t0 += 256) {
    int tok = t0 + t;
    int m0 = (top0[tok] == e), m1 = (top1[tok] == e);
    c0 += m0; c1 += m1;
    int matched = m0 | m1;
    unsigned long long mask = __ballot(matched);
    if (lane == 0) wco[wv] = __popcll(mask);
    __syncthreads();
    int off = base;
    for (int j = 0; j < wv; ++j) off += wco[j];
    int pos = off + __popcll(mask & ((1ull << lane) - 1ull));
    if (matched) {
      lst[e * NTOK + pos] = tok;
      tokslot[2 * tok + (m0 ? 0 : 1)] = (e << 16) | pos;
    }
    base += wco[0] + wco[1] + wco[2] + wco[3];
    __syncthreads();
  }
#pragma unroll
  for (int o = 32; o; o >>= 1) { c0 += __shfl_xor(c0, o); c1 += __shfl_xor(c1, o); }
  __shared__ int r0[4], r1[4];
  if (lane == 0) { r0[wv] = c0; r1[wv] = c1; }
  __syncthreads();
  if (t == 0) {
    ecnt[e] = base;
    cnt0[e] = r0[0] + r0[1] + r0[2] + r0[3];
    cnt1[e] = r1[0] + r1[1] + r1[2] + r1[3];
  }
}

// ---------------- gate-prob column sums (one block per expert) ----------------
__global__ __launch_bounds__(256) void lbsum_k(const float* __restrict__ probs8,
                                               float* __restrict__ probsum)
{
  int e = blockIdx.x, t = threadIdx.x;
  float s = 0.f;
  for (int tok = t; tok < NTOK; tok += 256) s += probs8[(long)tok * 8 + e];
#pragma unroll
  for (int o = 32; o; o >>= 1) s += __shfl_xor(s, o);
  __shared__ float r[4];
  if ((t & 63) == 0) r[t >> 6] = s;
  __syncthreads();
  if (t == 0) probsum[e] = r[0] + r[1] + r[2] + r[3];
}

__global__ void lb_k(const int* __restrict__ cnt0, const int* __restrict__ cnt1,
                     const float* __restrict__ probsum,
                     const float* __restrict__ lbin, float* __restrict__ out)
{
  if (threadIdx.x == 0 && blockIdx.x == 0) {
    float acc = 0.f;
    for (int e = 0; e < 8; ++e) acc += (float)(cnt0[e] + cnt1[e]) * probsum[e];
    out[0] = lbin[0] + acc * (4.0f / ((float)NTOK * (float)NTOK));
  }
}

extern "C" void kernel_launch(void* const* d_in, const int* in_sizes, int n_in,
                              void* d_out, int out_size, void* d_ws, size_t ws_size,
                              hipStream_t stream) {
  (void)in_sizes; (void)n_in; (void)out_size; (void)ws_size;
  const float* hid  = (const float*)d_in[0];
  const int*   pos  = (const int*)d_in[1];
  const float* lbin = (const float*)d_in[2];
  const float* ln1  = (const float*)d_in[3];
  const float* ln2  = (const float*)d_in[4];
  const float* Wq   = (const float*)d_in[5];
  const float* Wk   = (const float*)d_in[6];
  const float* Wv   = (const float*)d_in[7];
  const float* Wo   = (const float*)d_in[8];
  const float* Wg   = (const float*)d_in[9];
  const float* w1   = (const float*)d_in[10];
  const float* w2   = (const float*)d_in[11];
  const float* w3   = (const float*)d_in[12];
  float* out = (float*)d_out;

  char* ws = (char*)d_ws;
  size_t off = 0;
  auto alloc = [&](size_t bytes) { void* p = ws + off; off += (bytes + 255) & ~255ull; return p; };
  unsigned short* WqkvT = (unsigned short*)alloc(2048ull * 1024 * 2);
  unsigned short* WoT   = (unsigned short*)alloc(1024ull * 1024 * 2);
  unsigned short* w1T   = (unsigned short*)alloc((size_t)NE * FF * DM * 2);
  unsigned short* w3T   = (unsigned short*)alloc((size_t)NE * FF * DM * 2);
  unsigned short* w2T   = (unsigned short*)alloc((size_t)NE * DM * FF * 2);
  unsigned short* xn    = (unsigned short*)alloc((size_t)NTOK * DM * 2);
  unsigned short* vtg   = (unsigned short*)alloc((size_t)BATCH * NKV * 64 * SEQ * 2);
  unsigned short* ybuf  = (unsigned short*)alloc((size_t)(2 * NTOK) * DM * 2);
  int*   lst = (int*)alloc((size_t)NE * NTOK * 4);
  int*   tokslot = (int*)alloc((size_t)NTOK * 2 * 4);
  float* probs8 = (float*)alloc((size_t)NTOK * 8 * 4);
  int*   top0 = (int*)alloc((size_t)NTOK * 4);
  int*   top1 = (int*)alloc((size_t)NTOK * 4);
  float* wtop = (float*)alloc((size_t)NTOK * 2 * 4);
  int*   ctr = (int*)alloc(256);
  int*   ecnt = ctr;                    // [8]
  int*   cnt0 = ctr + 8;                // [8]
  int*   cnt1 = ctr + 16;               // [8]
  float* probsum = (float*)(ctr + 24);  // [8]
  size_t qkvB  = (size_t)NTOK * 2048 * 2;
  size_t aoutB = (size_t)NTOK * DM * 2;
  size_t hbufB = (size_t)(2 * NTOK + 256) * FF * 2;
  char* region = (char*)alloc(qkvB + aoutB > hbufB ? qkvB + aoutB : hbufB);
  unsigned short* qkv  = (unsigned short*)region;
  unsigned short* aout = (unsigned short*)(region + qkvB);
  unsigned short* hbuf = (unsigned short*)region;

  // weight transpose/convert
  transpose_cvt_k<<<dim3(16, 16, 1), 256, 0, stream>>>(Wq, WqkvT, 1024, 1024, 0, 0);
  transpose_cvt_k<<<dim3(8, 16, 1), 256, 0, stream>>>(Wk, WqkvT + 1024 * 1024, 1024, 512, 0, 0);
  transpose_cvt_k<<<dim3(8, 16, 1), 256, 0, stream>>>(Wv, WqkvT + 1536 * 1024, 1024, 512, 0, 0);
  transpose_cvt_k<<<dim3(16, 16, 1), 256, 0, stream>>>(Wo, WoT, 1024, 1024, 0, 0);
  transpose_cvt_k<<<dim3(FF / 64, 16, 8), 256, 0, stream>>>(w1, w1T, 1024, FF, (long)DM * FF, (long)FF * DM);
  transpose_cvt_k<<<dim3(FF / 64, 16, 8), 256, 0, stream>>>(w3, w3T, 1024, FF, (long)DM * FF, (long)FF * DM);
  transpose_cvt_k<<<dim3(16, FF / 64, 8), 256, 0, stream>>>(w2, w2T, FF, 1024, (long)FF * DM, (long)DM * FF);

  rmsnorm_k<<<NTOK, 256, 0, stream>>>(hid, ln1, xn);
  gemm_k<0><<<dim3(32, 16), 256, 0, stream>>>(xn, WqkvT, qkv, nullptr,
                                              NTOK, 2048, 1024, 1024, 1024, 2048);
  rope_k<<<NTOK, 256, 0, stream>>>(qkv, pos);
  vtrans_k<<<dim3(SEQ / 64, NKV, BATCH), 256, 0, stream>>>(qkv, vtg);
  attn_k<<<dim3(SEQ / 64, NKV, BATCH), 512, 0, stream>>>(qkv, vtg, aout);
  gemm_k<1><<<dim3(32, 8), 256, 0, stream>>>(aout, WoT, d_out, hid,
                                             NTOK, 1024, 1024, 1024, 1024, 1024);
  router_k<<<NTOK, 256, 0, stream>>>(out, ln2, Wg, xn, probs8, top0, top1, wtop);
  build_lists_k<<<8, 256, 0, stream>>>(top0, top1, wtop, lst, tokslot, ecnt, cnt0, cnt1);
  lbsum_k<<<8, 256, 0, stream>>>(probs8, probsum);
  // MoE: fused h = silu(x@w1)*(x@w3) -> hbuf; y = h@w2 -> ybuf; gather into out
  moe_up_k<<<768, 512, 0, stream>>>(xn, w1T, w3T, hbuf, lst, ecnt);
  moe_dn_k<<<768, 256, 0, stream>>>(hbuf, w2T, ybuf, ecnt);
  moe_gather_k<<<NTOK, 256, 0, stream>>>(ybuf, tokslot, wtop, ecnt, out);
  lb_k<<<1, 64, 0, stream>>>(cnt0, cnt1, probsum, lbin, out + (size_t)NTOK * DM);
}

// Round 11
// 524.905 us; speedup vs baseline: 3.3296x; 3.3296x over previous
//
#include <hip/hip_runtime.h>
#include <stdint.h>

#define DEV __device__ __forceinline__

typedef __attribute__((ext_vector_type(8))) short short8;
typedef __attribute__((ext_vector_type(4))) float f32x4;
typedef __attribute__((ext_vector_type(4))) short short4v;

static constexpr int BATCH = 2, SEQ = 2048, DM = 1024, NH = 16, NKV = 8, HD = 64;
static constexpr int NTOK = BATCH * SEQ;   // 4096
static constexpr int NE = 8, FF = 3584;

DEV unsigned short f2bf(float f) {
  union { float f; unsigned u; } x; x.f = f;
  unsigned r = x.u + 0x7fffu + ((x.u >> 16) & 1u);
  return (unsigned short)(r >> 16);
}
DEV float bf2f(unsigned short h) {
  union { unsigned u; float f; } x; x.u = ((unsigned)h) << 16; return x.f;
}

DEV void async16(const void* g, void* l) {
  __builtin_amdgcn_global_load_lds((const __attribute__((address_space(1))) unsigned int*)g,
                                   (__attribute__((address_space(3))) unsigned int*)l, 16, 0, 0);
}

DEV f32x4 mfma16(short8 a, short8 b, f32x4 c) {
  return __builtin_amdgcn_mfma_f32_16x16x32_bf16(a, b, c, 0, 0, 0);
}

// ---------------- transpose + fp32->bf16 convert (vectorized):  out[c][r] = bf16(in[r][c])
__global__ __launch_bounds__(256) void transpose_cvt_k(
    const float* __restrict__ in, unsigned short* __restrict__ out,
    int R, int C, long inStride, long outStride)
{
  __shared__ unsigned short tile[64][68];
  const float* src = in + (long)blockIdx.z * inStride;
  unsigned short* dst = out + (long)blockIdx.z * outStride;
  int r0 = blockIdx.y * 64, c0 = blockIdx.x * 64;
  int s4 = (threadIdx.x & 15) * 4, rr = threadIdx.x >> 4;   // 16 slots x 16 rows
#pragma unroll
  for (int i = 0; i < 4; ++i) {
    int r = rr + i * 16;
    float4 v = *(const float4*)(src + (long)(r0 + r) * C + c0 + s4);
    tile[r][s4 + 0] = f2bf(v.x); tile[r][s4 + 1] = f2bf(v.y);
    tile[r][s4 + 2] = f2bf(v.z); tile[r][s4 + 3] = f2bf(v.w);
  }
  __syncthreads();
#pragma unroll
  for (int i = 0; i < 4; ++i) {
    int c = rr + i * 16;
    union { unsigned short us[4]; short4v v; } o;
    o.us[0] = tile[s4 + 0][c]; o.us[1] = tile[s4 + 1][c];
    o.us[2] = tile[s4 + 2][c]; o.us[3] = tile[s4 + 3][c];
    *(short4v*)(dst + (long)(c0 + c) * R + r0 + s4) = o.v;
  }
}

// ---------------- rmsnorm (fp32 in, bf16 out) ----------------
__global__ __launch_bounds__(256) void rmsnorm_k(
    const float* __restrict__ x, const float* __restrict__ w, unsigned short* __restrict__ out)
{
  int row = blockIdx.x, t = threadIdx.x;
  const float4* xr = (const float4*)(x + (long)row * DM);
  float4 v = xr[t];
  float ss = v.x * v.x + v.y * v.y + v.z * v.z + v.w * v.w;
#pragma unroll
  for (int o = 32; o; o >>= 1) ss += __shfl_xor(ss, o);
  __shared__ float red[4];
  if ((t & 63) == 0) red[t >> 6] = ss;
  __syncthreads();
  float tot = red[0] + red[1] + red[2] + red[3];
  float rms = rsqrtf(tot * (1.0f / DM) + 1e-5f);
  float4 wv = ((const float4*)w)[t];
  union { unsigned short us[4]; short4v s; } o4;
  o4.us[0] = f2bf(v.x * rms * wv.x);
  o4.us[1] = f2bf(v.y * rms * wv.y);
  o4.us[2] = f2bf(v.z * rms * wv.z);
  o4.us[3] = f2bf(v.w * rms * wv.w);
  *(short4v*)(out + (long)row * DM + 4 * t) = o4.s;
}

// ---------------- dense 128x128 MFMA GEMM: C = A[M,K] * Bt[N,K]^T ----------------
// MODE 0: bf16 C out.  MODE 1: fp32 out = resid + acc.
template<int MODE>
__global__ __launch_bounds__(256) void gemm_k(
    const unsigned short* __restrict__ A, const unsigned short* __restrict__ B0,
    void* __restrict__ Cout, const float* __restrict__ resid,
    int M, int N, int K, int ldA, int ldB, int ldC)
{
  constexpr int BM = 128, BN = 128, BK = 64;
  __shared__ __align__(16) unsigned short As[BM * BK];
  __shared__ __align__(16) unsigned short Bs[BN * BK];
  int bm = blockIdx.x, bn = blockIdx.y;
  int t = threadIdx.x, w = t >> 6, l = t & 63, g = l >> 4, q = l & 15;
  int wm = w >> 1, wn = w & 1;

  const char* aSrc[4];
  const char* bSrc[4];
#pragma unroll
  for (int i = 0; i < 4; ++i) {
    int r = i * 32 + w * 8 + (l >> 3);
    aSrc[i] = (const char*)(A + (long)(bm * BM + r) * ldA) + (((l & 7) * 16) ^ ((r & 7) << 4));
    bSrc[i] = (const char*)(B0 + (long)(bn * BN + r) * ldB) + (((l & 7) * 16) ^ ((r & 7) << 4));
  }
  f32x4 acc[4][4];
#pragma unroll
  for (int mi = 0; mi < 4; ++mi)
#pragma unroll
    for (int ni = 0; ni < 4; ++ni) acc[mi][ni] = f32x4{0.f, 0.f, 0.f, 0.f};

  for (int k0 = 0; k0 < K; k0 += BK) {
#pragma unroll
    for (int i = 0; i < 4; ++i) {
      async16(aSrc[i] + (long)k0 * 2, &As[(i * 32 + w * 8) * BK]);
      async16(bSrc[i] + (long)k0 * 2, &Bs[(i * 32 + w * 8) * BK]);
    }
    asm volatile("s_waitcnt vmcnt(0)" ::: "memory");
    __syncthreads();
#pragma unroll
    for (int kk = 0; kk < 2; ++kk) {
      int col = (kk * 64 + g * 16) ^ ((q & 7) << 4);
      short8 af[4], bfm[4];
#pragma unroll
      for (int mi = 0; mi < 4; ++mi)
        af[mi] = *(const short8*)&As[(wm * 64 + mi * 16 + q) * BK + (col >> 1)];
#pragma unroll
      for (int ni = 0; ni < 4; ++ni)
        bfm[ni] = *(const short8*)&Bs[(wn * 64 + ni * 16 + q) * BK + (col >> 1)];
#pragma unroll
      for (int mi = 0; mi < 4; ++mi)
#pragma unroll
        for (int ni = 0; ni < 4; ++ni)
          acc[mi][ni] = mfma16(af[mi], bfm[ni], acc[mi][ni]);
    }
    __syncthreads();
  }
#pragma unroll
  for (int mi = 0; mi < 4; ++mi) {
#pragma unroll
    for (int r = 0; r < 4; ++r) {
      int grow = bm * BM + wm * 64 + mi * 16 + g * 4 + r;
#pragma unroll
      for (int ni = 0; ni < 4; ++ni) {
        int gcol = bn * BN + wn * 64 + ni * 16 + q;
        float v = acc[mi][ni][r];
        if (MODE == 0) {
          ((unsigned short*)Cout)[(long)grow * ldC + gcol] = f2bf(v);
        } else {
          long idx = (long)grow * ldC + gcol;
          ((float*)Cout)[idx] = resid[idx] + v;
        }
      }
    }
  }
}

// ------- persistent fused MoE up-proj (BN=64 dual-B, tb-outer/jj-inner for L2 reuse):
//         h = silu(x@w1)*(x@w3) -> hbuf, gathered A rows.  (round-9 schedule, VGPR-safe)
__global__ __launch_bounds__(256, 3) void moe_up_k(
    const unsigned short* __restrict__ xn, const unsigned short* __restrict__ w1T,
    const unsigned short* __restrict__ w3T, unsigned short* __restrict__ hbuf,
    const int* __restrict__ lstAll, const int* __restrict__ cntAll)
{
  constexpr int BM = 128, BN = 64, BK = 64, NBN = FF / BN;   // 56
  constexpr int NJJ = NBN / 8;                                // 7 bn-tiles per XCD
  __shared__ __align__(16) unsigned short As[BM * BK];
  __shared__ __align__(16) unsigned short Bs[2][BN * BK];
  int t = threadIdx.x, w = t >> 6, l = t & 63, g = l >> 4, q = l & 15;
  int wm = w >> 1, wn = w & 1;
  int xcd = blockIdx.x & 7, slot = blockIdx.x >> 3, SLOTS = gridDim.x >> 3;

  int TB = 0;
  for (int e = 0; e < NE; ++e) TB += (cntAll[e] + BM - 1) >> 7;

  for (int lidx = slot; lidx < TB * NJJ; lidx += SLOTS) {
    int tb = lidx / NJJ, jj = lidx - tb * NJJ;   // tb-outer: the 7 bn-tiles sharing an
    int bn = xcd + 8 * jj;                       // A-panel are consecutive -> L2-resident
    int e = 0, base = 0, cnt = 0, bm = 0;
    for (; e < NE; ++e) {
      cnt = cntAll[e];
      int te = (cnt + BM - 1) >> 7;
      if (tb < te) { bm = tb; break; }
      tb -= te; base += cnt;
    }
    const int* lst = lstAll + e * NTOK;
    const unsigned short* B0 = w1T + (size_t)e * FF * DM + (size_t)bn * BN * DM;
    const unsigned short* B1 = w3T + (size_t)e * FF * DM + (size_t)bn * BN * DM;

    const char* aSrc[4];
    const char* b0Src[2];
    const char* b1Src[2];
#pragma unroll
    for (int i = 0; i < 4; ++i) {
      int r = i * 32 + w * 8 + (l >> 3);
      int grow = bm * BM + r;
      int arow = lst[grow < cnt ? grow : 0];
      int swz = ((l & 7) * 16) ^ ((r & 7) << 4);
      aSrc[i] = (const char*)(xn + (long)arow * DM) + swz;
      if (i < 2) {
        b0Src[i] = (const char*)(B0 + (long)r * DM) + swz;
        b1Src[i] = (const char*)(B1 + (long)r * DM) + swz;
      }
    }
    f32x4 acc0[4][2], acc1[4][2];
#pragma unroll
    for (int mi = 0; mi < 4; ++mi)
#pragma unroll
      for (int ni = 0; ni < 2; ++ni) {
        acc0[mi][ni] = f32x4{0.f, 0.f, 0.f, 0.f};
        acc1[mi][ni] = f32x4{0.f, 0.f, 0.f, 0.f};
      }

    for (int k0 = 0; k0 < DM; k0 += BK) {
#pragma unroll
      for (int i = 0; i < 4; ++i)
        async16(aSrc[i] + (long)k0 * 2, &As[(i * 32 + w * 8) * BK]);
#pragma unroll
      for (int i = 0; i < 2; ++i) {
        async16(b0Src[i] + (long)k0 * 2, &Bs[0][(i * 32 + w * 8) * BK]);
        async16(b1Src[i] + (long)k0 * 2, &Bs[1][(i * 32 + w * 8) * BK]);
      }
      asm volatile("s_waitcnt vmcnt(0)" ::: "memory");
      __syncthreads();
#pragma unroll
      for (int kk = 0; kk < 2; ++kk) {
        int col = (kk * 64 + g * 16) ^ ((q & 7) << 4);
        short8 af[4], bf0[2], bf1[2];
#pragma unroll
        for (int mi = 0; mi < 4; ++mi)
          af[mi] = *(const short8*)&As[(wm * 64 + mi * 16 + q) * BK + (col >> 1)];
#pragma unroll
        for (int ni = 0; ni < 2; ++ni) {
          int r = wn * 32 + ni * 16 + q;
          bf0[ni] = *(const short8*)&Bs[0][r * BK + (col >> 1)];
          bf1[ni] = *(const short8*)&Bs[1][r * BK + (col >> 1)];
        }
#pragma unroll
        for (int mi = 0; mi < 4; ++mi)
#pragma unroll
          for (int ni = 0; ni < 2; ++ni) {
            acc0[mi][ni] = mfma16(af[mi], bf0[ni], acc0[mi][ni]);
            acc1[mi][ni] = mfma16(af[mi], bf1[ni], acc1[mi][ni]);
          }
      }
      __syncthreads();
    }
#pragma unroll
    for (int mi = 0; mi < 4; ++mi) {
#pragma unroll
      for (int r = 0; r < 4; ++r) {
        int grow = bm * BM + wm * 64 + mi * 16 + g * 4 + r;
        if (grow >= cnt) continue;
        unsigned short* hp = hbuf + (size_t)(base + grow) * FF + bn * BN + wn * 32;
#pragma unroll
        for (int ni = 0; ni < 2; ++ni) {
          float v1 = acc0[mi][ni][r];
          float v3 = acc1[mi][ni][r];
          float sg = v1 / (1.0f + __expf(-v1));
          hp[ni * 16 + q] = f2bf(sg * v3);
        }
      }
    }
  }
}

// ------- persistent MoE down-proj (bn==XCD, BN=128, single-buffer m97 schedule):
//         y = h @ w2 -> ybuf slot-major.
__global__ __launch_bounds__(256, 3) void moe_dn_k(
    const unsigned short* __restrict__ hbuf, const unsigned short* __restrict__ w2T,
    unsigned short* __restrict__ ybuf, const int* __restrict__ cntAll)
{
  constexpr int BM = 128, BN = 128, BK = 64;                 // DM/BN == 8 == NXCD
  __shared__ __align__(16) unsigned short As[BM * BK];
  __shared__ __align__(16) unsigned short Bs[BN * BK];
  int t = threadIdx.x, w = t >> 6, l = t & 63, g = l >> 4, q = l & 15;
  int wm = w >> 1, wn = w & 1;
  int xcd = blockIdx.x & 7, slot = blockIdx.x >> 3, SLOTS = gridDim.x >> 3;
  int bn = xcd;

  int TB = 0;
  for (int e = 0; e < NE; ++e) TB += (cntAll[e] + BM - 1) >> 7;

  for (int tb0 = slot; tb0 < TB; tb0 += SLOTS) {
    int tb = tb0;
    int e = 0, base = 0, cnt = 0, bm = 0;
    for (; e < NE; ++e) {
      cnt = cntAll[e];
      int te = (cnt + BM - 1) >> 7;
      if (tb < te) { bm = tb; break; }
      tb -= te; base += cnt;
    }
    const unsigned short* B0 = w2T + (size_t)e * DM * FF + (size_t)bn * BN * FF;

    const char* aSrc[4];
    const char* bSrc[4];
#pragma unroll
    for (int i = 0; i < 4; ++i) {
      int r = i * 32 + w * 8 + (l >> 3);
      int grow = bm * BM + r;
      int arow = base + (grow < cnt ? grow : 0);
      int swz = ((l & 7) * 16) ^ ((r & 7) << 4);
      aSrc[i] = (const char*)(hbuf + (long)arow * FF) + swz;
      bSrc[i] = (const char*)(B0 + (long)r * FF) + swz;
    }
    f32x4 acc[4][4];
#pragma unroll
    for (int mi = 0; mi < 4; ++mi)
#pragma unroll
      for (int ni = 0; ni < 4; ++ni) acc[mi][ni] = f32x4{0.f, 0.f, 0.f, 0.f};

    for (int k0 = 0; k0 < FF; k0 += BK) {
#pragma unroll
      for (int i = 0; i < 4; ++i) {
        async16(aSrc[i] + (long)k0 * 2, &As[(i * 32 + w * 8) * BK]);
        async16(bSrc[i] + (long)k0 * 2, &Bs[(i * 32 + w * 8) * BK]);
      }
      asm volatile("s_waitcnt vmcnt(0)" ::: "memory");
      __syncthreads();
#pragma unroll
      for (int kk = 0; kk < 2; ++kk) {
        int col = (kk * 64 + g * 16) ^ ((q & 7) << 4);
        short8 af[4], bfm[4];
#pragma unroll
        for (int mi = 0; mi < 4; ++mi)
          af[mi] = *(const short8*)&As[(wm * 64 + mi * 16 + q) * BK + (col >> 1)];
#pragma unroll
        for (int ni = 0; ni < 4; ++ni)
          bfm[ni] = *(const short8*)&Bs[(wn * 64 + ni * 16 + q) * BK + (col >> 1)];
#pragma unroll
        for (int mi = 0; mi < 4; ++mi)
#pragma unroll
          for (int ni = 0; ni < 4; ++ni)
            acc[mi][ni] = mfma16(af[mi], bfm[ni], acc[mi][ni]);
      }
      __syncthreads();
    }
#pragma unroll
    for (int mi = 0; mi < 4; ++mi) {
#pragma unroll
      for (int r = 0; r < 4; ++r) {
        int grow = bm * BM + wm * 64 + mi * 16 + g * 4 + r;
        if (grow >= cnt) continue;
        unsigned short* yp = ybuf + (size_t)(base + grow) * DM + bn * BN + wn * 64;
#pragma unroll
        for (int ni = 0; ni < 4; ++ni)
          yp[ni * 16 + q] = f2bf(acc[mi][ni][r]);
      }
    }
  }
}

// ---------------- final MoE gather: out[tok] += w0*y[slot0] + w1*y[slot1] --------------
__global__ __launch_bounds__(256) void moe_gather_k(
    const unsigned short* __restrict__ ybuf, const int* __restrict__ tokslot,
    const float* __restrict__ wtop, const int* __restrict__ cntAll,
    float* __restrict__ out)
{
  __shared__ int base8[NE];
  int tok = blockIdx.x, t = threadIdx.x;
  if (t < NE) {
    int b = 0;
    for (int i = 0; i < t; ++i) b += cntAll[i];
    base8[t] = b;
  }
  __syncthreads();
  int s0 = tokslot[2 * tok], s1 = tokslot[2 * tok + 1];
  int slot0 = base8[s0 >> 16] + (s0 & 0xffff);
  int slot1 = base8[s1 >> 16] + (s1 & 0xffff);
  float w0 = wtop[2 * tok], w1 = wtop[2 * tok + 1];
  short4v a = *(const short4v*)(ybuf + (size_t)slot0 * DM + 4 * t);
  short4v b = *(const short4v*)(ybuf + (size_t)slot1 * DM + 4 * t);
  float4* op = (float4*)(out + (size_t)tok * DM);
  float4 o = op[t];
  o.x += w0 * bf2f((unsigned short)a[0]) + w1 * bf2f((unsigned short)b[0]);
  o.y += w0 * bf2f((unsigned short)a[1]) + w1 * bf2f((unsigned short)b[1]);
  o.z += w0 * bf2f((unsigned short)a[2]) + w1 * bf2f((unsigned short)b[2]);
  o.w += w0 * bf2f((unsigned short)a[3]) + w1 * bf2f((unsigned short)b[3]);
  op[t] = o;
}

// ---------------- RoPE (in-place on qkv bf16 buffer) ----------------
__global__ __launch_bounds__(256) void rope_k(unsigned short* __restrict__ qkv,
                                              const int* __restrict__ pos)
{
  int tok = blockIdx.x, t = threadIdx.x;
  __shared__ float cs[32], sn[32];
  if (t < 32) {
    float p = (float)pos[tok];
    float freq = __expf(-(float)t * 0.28782313663f);  // ln(10000)/32
    float a = p * freq;
    cs[t] = cosf(a); sn[t] = sinf(a);
  }
  __syncthreads();
  unsigned short* row = qkv + (long)tok * 2048;
#pragma unroll
  for (int idx = t; idx < 768; idx += 256) {
    int hh = idx >> 5, d = idx & 31;
    int col = (hh < 16) ? hh * 64 + d : 1024 + (hh - 16) * 64 + d;
    float x1 = bf2f(row[col]), x2 = bf2f(row[col + 32]);
    row[col]      = f2bf(x1 * cs[d] - x2 * sn[d]);
    row[col + 32] = f2bf(x2 * cs[d] + x1 * sn[d]);
  }
}

// ---------------- V transpose: qkv V-section -> VtG[b][kvh][d=64][S] ----------------
__global__ __launch_bounds__(256) void vtrans_k(const unsigned short* __restrict__ qkv,
                                                unsigned short* __restrict__ vt)
{
  __shared__ unsigned short tile[64][72];
  int s0 = blockIdx.x * 64, kvh = blockIdx.y, b = blockIdx.z;
  int t = threadIdx.x;
  int tx4 = (t & 15) * 4, row = t >> 4;
  const unsigned short* src = qkv + (long)(b * SEQ + s0) * 2048 + 1536 + kvh * 64;
#pragma unroll
  for (int i = 0; i < 4; ++i) {
    int r = row + i * 16;
    *(short4v*)&tile[r][tx4] = *(const short4v*)(src + (long)r * 2048 + tx4);
  }
  __syncthreads();
  unsigned short* dst = vt + (long)((b * NKV + kvh) * 64) * SEQ + s0;
#pragma unroll
  for (int i = 0; i < 4; ++i) {
    int d = row + i * 16;
    union { unsigned short us[4]; short4v v; } o;
    o.us[0] = tile[tx4 + 0][d]; o.us[1] = tile[tx4 + 1][d];
    o.us[2] = tile[tx4 + 2][d]; o.us[3] = tile[tx4 + 3][d];
    *(short4v*)(dst + (long)d * SEQ + tx4) = o.v;
  }
}

// ---------------- causal GQA flash attention (512 thr: 2 heads of one KV group) --------
__global__ __launch_bounds__(512) void attn_k(const unsigned short* __restrict__ qkv,
                                              const unsigned short* __restrict__ vtg,
                                              unsigned short* __restrict__ aout)
{
  int b = blockIdx.z;
  int qt = b ? (31 - blockIdx.x) : blockIdx.x;
  int kvh = blockIdx.y;
  int t = threadIdx.x, w = t >> 6, l = t & 63, g = l >> 4, q = l & 15;
  int h = kvh * 2 + (w >> 2);
  int wl = w & 3;
  __shared__ __align__(16) unsigned short Ks[2][4096];
  __shared__ __align__(16) unsigned short Vs[2][4096];
  int tok0 = b * SEQ;
  int myq = qt * 64 + wl * 16 + q;
  const unsigned short* qp = qkv + (long)(tok0 + myq) * 2048 + h * 64;
  short8 qf0 = *(const short8*)(qp + g * 8);
  short8 qf1 = *(const short8*)(qp + 32 + g * 8);
  const unsigned short* vtb = vtg + (long)((b * NKV + kvh) * 64) * SEQ;
  f32x4 o[4];
#pragma unroll
  for (int nf = 0; nf < 4; ++nf) o[nf] = f32x4{0.f, 0.f, 0.f, 0.f};
  float m = -1e30f, ssum = 0.0f;
  int r8 = w * 8 + (l >> 3);
  int sswz = ((l & 7) * 16) ^ ((r8 & 7) << 4);

  auto stage = [&](int kt, int buf) {
    const char* ksrc = (const char*)(qkv + (long)(tok0 + kt * 64 + r8) * 2048 + 1024 + kvh * 64) + sswz;
    async16(ksrc, &Ks[buf][r8 * 64]);
    const char* vsrc = (const char*)(vtb + (long)r8 * SEQ + kt * 64) + sswz;
    async16(vsrc, &Vs[buf][r8 * 64]);
  };

  stage(0, 0);
  __syncthreads();
  int cur = 0;
  for (int kt = 0; kt <= qt; ++kt) {
    if (kt < qt) stage(kt + 1, cur ^ 1);
    f32x4 st[4];
#pragma unroll
    for (int mb = 0; mb < 4; ++mb) {
      int kr = mb * 16 + q;
      int c0 = (g * 16) ^ ((q & 7) << 4);
      int c1 = (64 + g * 16) ^ ((q & 7) << 4);
      short8 k0 = *(const short8*)&Ks[cur][kr * 64 + (c0 >> 1)];
      short8 k1 = *(const short8*)&Ks[cur][kr * 64 + (c1 >> 1)];
      f32x4 z = f32x4{0.f, 0.f, 0.f, 0.f};
      __builtin_amdgcn_s_setprio(1);
      z = mfma16(k0, qf0, z);
      z = mfma16(k1, qf1, z);
      __builtin_amdgcn_s_setprio(0);
      st[mb] = z;
    }
    float p[4][4];
    float tmax = -1e30f;
#pragma unroll
    for (int mb = 0; mb < 4; ++mb)
#pragma unroll
      for (int r = 0; r < 4; ++r) {
        float v = st[mb][r] * 0.125f;
        int kvg = kt * 64 + mb * 16 + g * 4 + r;
        if (kvg > myq) v = -1e30f;
        p[mb][r] = v;
        tmax = fmaxf(tmax, v);
      }
    tmax = fmaxf(tmax, __shfl_xor(tmax, 16));
    tmax = fmaxf(tmax, __shfl_xor(tmax, 32));
    float mnew = fmaxf(m, tmax);
    float fac = __expf(m - mnew);
    m = mnew;
    float ps = 0.0f;
#pragma unroll
    for (int mb = 0; mb < 4; ++mb)
#pragma unroll
      for (int r = 0; r < 4; ++r) { float e = __expf(p[mb][r] - m); p[mb][r] = e; ps += e; }
    ps += __shfl_xor(ps, 16);
    ps += __shfl_xor(ps, 32);
    ssum = ssum * fac + ps;
#pragma unroll
    for (int r = 0; r < 4; ++r) {
      float ff = __shfl(fac, g * 4 + r);
#pragma unroll
      for (int nf = 0; nf < 4; ++nf) o[nf][r] *= ff;
    }
    unsigned pw[4][2];
#pragma unroll
    for (int mb = 0; mb < 4; ++mb) {
      pw[mb][0] = ((unsigned)f2bf(p[mb][1]) << 16) | f2bf(p[mb][0]);
      pw[mb][1] = ((unsigned)f2bf(p[mb][3]) << 16) | f2bf(p[mb][2]);
    }
    short8 pa[2];
#pragma unroll
    for (int f = 0; f < 2; ++f) {
      union { unsigned u[4]; short8 s; } cv;
#pragma unroll
      for (int i = 0; i < 4; ++i) {
        int srcl = ((g & 1) * 2 + (i >> 1)) * 16 + q;
        unsigned aa = (unsigned)__shfl((int)pw[2 * f][i & 1], srcl);
        unsigned bb = (unsigned)__shfl((int)pw[2 * f + 1][i & 1], srcl);
        cv.u[i] = (g & 2) ? bb : aa;
      }
      pa[f] = cv.s;
    }
#pragma unroll
    for (int kk = 0; kk < 2; ++kk) {
      int cb = (kk * 64 + g * 16) ^ ((q & 7) << 4);
      __builtin_amdgcn_s_setprio(1);
#pragma unroll
      for (int nf = 0; nf < 4; ++nf) {
        short8 vb = *(const short8*)&Vs[cur][(nf * 16 + q) * 64 + (cb >> 1)];
        o[nf] = mfma16(pa[kk], vb, o[nf]);
      }
      __builtin_amdgcn_s_setprio(0);
    }
    __syncthreads();
    cur ^= 1;
  }
#pragma unroll
  for (int r = 0; r < 4; ++r) {
    float is = 1.0f / __shfl(ssum, g * 4 + r);
    int orow = tok0 + qt * 64 + wl * 16 + g * 4 + r;
    unsigned short* op = aout + (long)orow * 1024 + h * 64;
    op[q]      = f2bf(o[0][r] * is);
    op[16 + q] = f2bf(o[1][r] * is);
    op[32 + q] = f2bf(o[2][r] * is);
    op[48 + q] = f2bf(o[3][r] * is);
  }
}

// ---------------- rmsnorm2 + router (atomic-free: per-token writes only) ----------------
__global__ __launch_bounds__(256) void router_k(
    const float* __restrict__ hid, const float* __restrict__ w2n, const float* __restrict__ Wg,
    unsigned short* __restrict__ xn, float* __restrict__ probs8,
    int* __restrict__ top0, int* __restrict__ top1, float* __restrict__ wtop)
{
  int row = blockIdx.x, t = threadIdx.x;
  const float4* xr = (const float4*)(hid + (long)row * DM);
  float4 v = xr[t];
  float ss = v.x * v.x + v.y * v.y + v.z * v.z + v.w * v.w;
#pragma unroll
  for (int o = 32; o; o >>= 1) ss += __shfl_xor(ss, o);
  __shared__ float red[4];
  __shared__ float lred[4][8];
  __shared__ float lg[8];
  if ((t & 63) == 0) red[t >> 6] = ss;
  __syncthreads();
  float tot = red[0] + red[1] + red[2] + red[3];
  float rms = rsqrtf(tot * (1.0f / DM) + 1e-5f);
  float4 wv = ((const float4*)w2n)[t];
  float x0 = v.x * rms * wv.x, x1 = v.y * rms * wv.y, x2 = v.z * rms * wv.z, x3 = v.w * rms * wv.w;
  union { unsigned short us[4]; short4v s; } o4;
  o4.us[0] = f2bf(x0); o4.us[1] = f2bf(x1); o4.us[2] = f2bf(x2); o4.us[3] = f2bf(x3);
  *(short4v*)(xn + (long)row * DM + 4 * t) = o4.s;
  const float* wgr = Wg + t * 32;
  float lacc[8];
#pragma unroll
  for (int e = 0; e < 8; ++e)
    lacc[e] = x0 * wgr[e] + x1 * wgr[8 + e] + x2 * wgr[16 + e] + x3 * wgr[24 + e];
#pragma unroll
  for (int e = 0; e < 8; ++e)
#pragma unroll
    for (int o = 32; o; o >>= 1) lacc[e] += __shfl_xor(lacc[e], o);
  if ((t & 63) == 0)
#pragma unroll
    for (int e = 0; e < 8; ++e) lred[t >> 6][e] = lacc[e];
  __syncthreads();
  if (t < 8) lg[t] = lred[0][t] + lred[1][t] + lred[2][t] + lred[3][t];
  __syncthreads();
  if (t == 0) {
    float p[8];
    float mx = lg[0];
#pragma unroll
    for (int e = 1; e < 8; ++e) mx = fmaxf(mx, lg[e]);
    float s = 0.f;
#pragma unroll
    for (int e = 0; e < 8; ++e) { p[e] = __expf(lg[e] - mx); s += p[e]; }
    float isv = 1.0f / s;
#pragma unroll
    for (int e = 0; e < 8; ++e) { p[e] *= isv; probs8[(long)row * 8 + e] = p[e]; }
    int i0 = 0;
#pragma unroll
    for (int e = 1; e < 8; ++e) if (p[e] > p[i0]) i0 = e;
    int i1 = (i0 == 0) ? 1 : 0;
#pragma unroll
    for (int e = 0; e < 8; ++e) if (e != i0 && p[e] > p[i1]) i1 = e;
    float sw = p[i0] + p[i1];
    top0[row] = i0; top1[row] = i1;
    wtop[2 * row] = p[i0] / sw; wtop[2 * row + 1] = p[i1] / sw;
  }
}

// ---------------- expert list compaction (deterministic, no atomics) ----------------
__global__ __launch_bounds__(256) void build_lists_k(
    const int* __restrict__ top0, const int* __restrict__ top1,
    const float* __restrict__ wtop, int* __restrict__ lst, int* __restrict__ tokslot,
    int* __restrict__ ecnt, int* __restrict__ cnt0, int* __restrict__ cnt1)
{
  int e = blockIdx.x, t = threadIdx.x, lane = t & 63, wv = t >> 6;
  __shared__ int wco[4];
  int base = 0, c0 = 0, c1 = 0;
  for (int t0 = 0; t0 < NTOK; t0 += 256) {
    int tok = t0 + t;
    int m0 = (top0[tok] == e), m1 = (top1[tok] == e);
    c0 += m0; c1 += m1;
    int matched = m0 | m1;
    unsigned long long mask = __ballot(matched);
    if (lane == 0) wco[wv] = __popcll(mask);
    __syncthreads();
    int off = base;
    for (int j = 0; j < wv; ++j) off += wco[j];
    int pos = off + __popcll(mask & ((1ull << lane) - 1ull));
    if (matched) {
      lst[e * NTOK + pos] = tok;
      tokslot[2 * tok + (m0 ? 0 : 1)] = (e << 16) | pos;
    }
    base += wco[0] + wco[1] + wco[2] + wco[3];
    __syncthreads();
  }
#pragma unroll
  for (int o = 32; o; o >>= 1) { c0 += __shfl_xor(c0, o); c1 += __shfl_xor(c1, o); }
  __shared__ int r0[4], r1[4];
  if (lane == 0) { r0[wv] = c0; r1[wv] = c1; }
  __syncthreads();
  if (t == 0) {
    ecnt[e] = base;
    cnt0[e] = r0[0] + r0[1] + r0[2] + r0[3];
    cnt1[e] = r1[0] + r1[1] + r1[2] + r1[3];
  }
}

// ---------------- gate-prob column sums (one block per expert) ----------------
__global__ __launch_bounds__(256) void lbsum_k(const float* __restrict__ probs8,
                                               float* __restrict__ probsum)
{
  int e = blockIdx.x, t = threadIdx.x;
  float s = 0.f;
  for (int tok = t; tok < NTOK; tok += 256) s += probs8[(long)tok * 8 + e];
#pragma unroll
  for (int o = 32; o; o >>= 1) s += __shfl_xor(s, o);
  __shared__ float r[4];
  if ((t & 63) == 0) r[t >> 6] = s;
  __syncthreads();
  if (t == 0) probsum[e] = r[0] + r[1] + r[2] + r[3];
}

__global__ void lb_k(const int* __restrict__ cnt0, const int* __restrict__ cnt1,
                     const float* __restrict__ probsum,
                     const float* __restrict__ lbin, float* __restrict__ out)
{
  if (threadIdx.x == 0 && blockIdx.x == 0) {
    float acc = 0.f;
    for (int e = 0; e < 8; ++e) acc += (float)(cnt0[e] + cnt1[e]) * probsum[e];
    out[0] = lbin[0] + acc * (4.0f / ((float)NTOK * (float)NTOK));
  }
}

extern "C" void kernel_launch(void* const* d_in, const int* in_sizes, int n_in,
                              void* d_out, int out_size, void* d_ws, size_t ws_size,
                              hipStream_t stream) {
  (void)in_sizes; (void)n_in; (void)out_size; (void)ws_size;
  const float* hid  = (const float*)d_in[0];
  const int*   pos  = (const int*)d_in[1];
  const float* lbin = (const float*)d_in[2];
  const float* ln1  = (const float*)d_in[3];
  const float* ln2  = (const float*)d_in[4];
  const float* Wq   = (const float*)d_in[5];
  const float* Wk   = (const float*)d_in[6];
  const float* Wv   = (const float*)d_in[7];
  const float* Wo   = (const float*)d_in[8];
  const float* Wg   = (const float*)d_in[9];
  const float* w1   = (const float*)d_in[10];
  const float* w2   = (const float*)d_in[11];
  const float* w3   = (const float*)d_in[12];
  float* out = (float*)d_out;

  char* ws = (char*)d_ws;
  size_t off = 0;
  auto alloc = [&](size_t bytes) { void* p = ws + off; off += (bytes + 255) & ~255ull; return p; };
  unsigned short* WqkvT = (unsigned short*)alloc(2048ull * 1024 * 2);
  unsigned short* WoT   = (unsigned short*)alloc(1024ull * 1024 * 2);
  unsigned short* w1T   = (unsigned short*)alloc((size_t)NE * FF * DM * 2);
  unsigned short* w3T   = (unsigned short*)alloc((size_t)NE * FF * DM * 2);
  unsigned short* w2T   = (unsigned short*)alloc((size_t)NE * DM * FF * 2);
  unsigned short* xn    = (unsigned short*)alloc((size_t)NTOK * DM * 2);
  unsigned short* vtg   = (unsigned short*)alloc((size_t)BATCH * NKV * 64 * SEQ * 2);
  unsigned short* ybuf  = (unsigned short*)alloc((size_t)(2 * NTOK) * DM * 2);
  int*   lst = (int*)alloc((size_t)NE * NTOK * 4);
  int*   tokslot = (int*)alloc((size_t)NTOK * 2 * 4);
  float* probs8 = (float*)alloc((size_t)NTOK * 8 * 4);
  int*   top0 = (int*)alloc((size_t)NTOK * 4);
  int*   top1 = (int*)alloc((size_t)NTOK * 4);
  float* wtop = (float*)alloc((size_t)NTOK * 2 * 4);
  int*   ctr = (int*)alloc(256);
  int*   ecnt = ctr;                    // [8]
  int*   cnt0 = ctr + 8;                // [8]
  int*   cnt1 = ctr + 16;               // [8]
  float* probsum = (float*)(ctr + 24);  // [8]
  size_t qkvB  = (size_t)NTOK * 2048 * 2;
  size_t aoutB = (size_t)NTOK * DM * 2;
  size_t hbufB = (size_t)(2 * NTOK + 128) * FF * 2;
  char* region = (char*)alloc(qkvB + aoutB > hbufB ? qkvB + aoutB : hbufB);
  unsigned short* qkv  = (unsigned short*)region;
  unsigned short* aout = (unsigned short*)(region + qkvB);
  unsigned short* hbuf = (unsigned short*)region;

  // weight transpose/convert
  transpose_cvt_k<<<dim3(16, 16, 1), 256, 0, stream>>>(Wq, WqkvT, 1024, 1024, 0, 0);
  transpose_cvt_k<<<dim3(8, 16, 1), 256, 0, stream>>>(Wk, WqkvT + 1024 * 1024, 1024, 512, 0, 0);
  transpose_cvt_k<<<dim3(8, 16, 1), 256, 0, stream>>>(Wv, WqkvT + 1536 * 1024, 1024, 512, 0, 0);
  transpose_cvt_k<<<dim3(16, 16, 1), 256, 0, stream>>>(Wo, WoT, 1024, 1024, 0, 0);
  transpose_cvt_k<<<dim3(FF / 64, 16, 8), 256, 0, stream>>>(w1, w1T, 1024, FF, (long)DM * FF, (long)FF * DM);
  transpose_cvt_k<<<dim3(FF / 64, 16, 8), 256, 0, stream>>>(w3, w3T, 1024, FF, (long)DM * FF, (long)FF * DM);
  transpose_cvt_k<<<dim3(16, FF / 64, 8), 256, 0, stream>>>(w2, w2T, FF, 1024, (long)FF * DM, (long)DM * FF);

  rmsnorm_k<<<NTOK, 256, 0, stream>>>(hid, ln1, xn);
  gemm_k<0><<<dim3(32, 16), 256, 0, stream>>>(xn, WqkvT, qkv, nullptr,
                                              NTOK, 2048, 1024, 1024, 1024, 2048);
  rope_k<<<NTOK, 256, 0, stream>>>(qkv, pos);
  vtrans_k<<<dim3(SEQ / 64, NKV, BATCH), 256, 0, stream>>>(qkv, vtg);
  attn_k<<<dim3(SEQ / 64, NKV, BATCH), 512, 0, stream>>>(qkv, vtg, aout);
  gemm_k<1><<<dim3(32, 8), 256, 0, stream>>>(aout, WoT, d_out, hid,
                                             NTOK, 1024, 1024, 1024, 1024, 1024);
  router_k<<<NTOK, 256, 0, stream>>>(out, ln2, Wg, xn, probs8, top0, top1, wtop);
  build_lists_k<<<8, 256, 0, stream>>>(top0, top1, wtop, lst, tokslot, ecnt, cnt0, cnt1);
  lbsum_k<<<8, 256, 0, stream>>>(probs8, probsum);
  // MoE: fused h = silu(x@w1)*(x@w3) -> hbuf; y = h@w2 -> ybuf; gather into out
  moe_up_k<<<768, 256, 0, stream>>>(xn, w1T, w3T, hbuf, lst, ecnt);
  moe_dn_k<<<768, 256, 0, stream>>>(hbuf, w2T, ybuf, ecnt);
  moe_gather_k<<<NTOK, 256, 0, stream>>>(ybuf, tokslot, wtop, ecnt, out);
  lb_k<<<1, 64, 0, stream>>>(cnt0, cnt1, probsum, lbin, out + (size_t)NTOK * DM);
}

// Round 12
// 502.099 us; speedup vs baseline: 3.4808x; 1.0454x over previous
//
#include <hip/hip_runtime.h>
#include <stdint.h>

#define DEV __device__ __forceinline__

typedef __attribute__((ext_vector_type(8))) short short8;
typedef __attribute__((ext_vector_type(4))) float f32x4;
typedef __attribute__((ext_vector_type(4))) short short4v;

static constexpr int BATCH = 2, SEQ = 2048, DM = 1024, NH = 16, NKV = 8, HD = 64;
static constexpr int NTOK = BATCH * SEQ;   // 4096
static constexpr int NE = 8, FF = 3584;

DEV unsigned short f2bf(float f) {
  union { float f; unsigned u; } x; x.f = f;
  unsigned r = x.u + 0x7fffu + ((x.u >> 16) & 1u);
  return (unsigned short)(r >> 16);
}
DEV float bf2f(unsigned short h) {
  union { unsigned u; float f; } x; x.u = ((unsigned)h) << 16; return x.f;
}

DEV void async16(const void* g, void* l) {
  __builtin_amdgcn_global_load_lds((const __attribute__((address_space(1))) unsigned int*)g,
                                   (__attribute__((address_space(3))) unsigned int*)l, 16, 0, 0);
}

DEV f32x4 mfma16(short8 a, short8 b, f32x4 c) {
  return __builtin_amdgcn_mfma_f32_16x16x32_bf16(a, b, c, 0, 0, 0);
}

// ---------------- ALL weight transposes in one dispatch ----------------
// tile body identical to the proven transpose_cvt_k; range-decoded geometry.
__global__ __launch_bounds__(256) void transpose_all_k(
    const float* __restrict__ Wq, const float* __restrict__ Wk, const float* __restrict__ Wv,
    const float* __restrict__ Wo, const float* __restrict__ w1, const float* __restrict__ w2,
    const float* __restrict__ w3, unsigned short* __restrict__ WqkvT,
    unsigned short* __restrict__ WoT, unsigned short* __restrict__ w1T,
    unsigned short* __restrict__ w3T, unsigned short* __restrict__ w2T)
{
  __shared__ unsigned short tile[64][68];
  int idx = blockIdx.x;
  const float* in; unsigned short* out; int R, C; int r0, c0;
  if (idx < 256) {                // Wq 1024x1024
    in = Wq; out = WqkvT; R = 1024; C = 1024;
    c0 = (idx & 15) * 64; r0 = (idx >> 4) * 64;
  } else if (idx < 512) {         // Wo 1024x1024
    idx -= 256; in = Wo; out = WoT; R = 1024; C = 1024;
    c0 = (idx & 15) * 64; r0 = (idx >> 4) * 64;
  } else if (idx < 640) {         // Wk 1024x512
    idx -= 512; in = Wk; out = WqkvT + 1024 * 1024; R = 1024; C = 512;
    c0 = (idx & 7) * 64; r0 = (idx >> 3) * 64;
  } else if (idx < 768) {         // Wv 1024x512
    idx -= 640; in = Wv; out = WqkvT + 1536 * 1024; R = 1024; C = 512;
    c0 = (idx & 7) * 64; r0 = (idx >> 3) * 64;
  } else if (idx < 768 + 7168) {  // w1[e] 1024xFF
    idx -= 768; int e = idx / 896, rem = idx % 896;
    in = w1 + (long)e * DM * FF; out = w1T + (size_t)e * FF * DM; R = 1024; C = FF;
    c0 = (rem % 56) * 64; r0 = (rem / 56) * 64;
  } else if (idx < 768 + 14336) { // w3[e] 1024xFF
    idx -= 768 + 7168; int e = idx / 896, rem = idx % 896;
    in = w3 + (long)e * DM * FF; out = w3T + (size_t)e * FF * DM; R = 1024; C = FF;
    c0 = (rem % 56) * 64; r0 = (rem / 56) * 64;
  } else {                        // w2[e] FFx1024
    idx -= 768 + 14336; int e = idx / 896, rem = idx % 896;
    in = w2 + (long)e * FF * DM; out = w2T + (size_t)e * DM * FF; R = FF; C = 1024;
    c0 = (rem % 16) * 64; r0 = (rem / 16) * 64;
  }
  int s4 = (threadIdx.x & 15) * 4, rr = threadIdx.x >> 4;
#pragma unroll
  for (int i = 0; i < 4; ++i) {
    int r = rr + i * 16;
    float4 v = *(const float4*)(in + (long)(r0 + r) * C + c0 + s4);
    tile[r][s4 + 0] = f2bf(v.x); tile[r][s4 + 1] = f2bf(v.y);
    tile[r][s4 + 2] = f2bf(v.z); tile[r][s4 + 3] = f2bf(v.w);
  }
  __syncthreads();
#pragma unroll
  for (int i = 0; i < 4; ++i) {
    int c = rr + i * 16;
    union { unsigned short us[4]; short4v v; } o;
    o.us[0] = tile[s4 + 0][c]; o.us[1] = tile[s4 + 1][c];
    o.us[2] = tile[s4 + 2][c]; o.us[3] = tile[s4 + 3][c];
    *(short4v*)(out + (long)(c0 + c) * R + r0 + s4) = o.v;
  }
}

// ---------------- rmsnorm (fp32 in, bf16 out) ----------------
__global__ __launch_bounds__(256) void rmsnorm_k(
    const float* __restrict__ x, const float* __restrict__ w, unsigned short* __restrict__ out)
{
  int row = blockIdx.x, t = threadIdx.x;
  const float4* xr = (const float4*)(x + (long)row * DM);
  float4 v = xr[t];
  float ss = v.x * v.x + v.y * v.y + v.z * v.z + v.w * v.w;
#pragma unroll
  for (int o = 32; o; o >>= 1) ss += __shfl_xor(ss, o);
  __shared__ float red[4];
  if ((t & 63) == 0) red[t >> 6] = ss;
  __syncthreads();
  float tot = red[0] + red[1] + red[2] + red[3];
  float rms = rsqrtf(tot * (1.0f / DM) + 1e-5f);
  float4 wv = ((const float4*)w)[t];
  union { unsigned short us[4]; short4v s; } o4;
  o4.us[0] = f2bf(v.x * rms * wv.x);
  o4.us[1] = f2bf(v.y * rms * wv.y);
  o4.us[2] = f2bf(v.z * rms * wv.z);
  o4.us[3] = f2bf(v.w * rms * wv.w);
  *(short4v*)(out + (long)row * DM + 4 * t) = o4.s;
}

// ---------------- dense 128x128 MFMA GEMM: C = A[M,K] * Bt[N,K]^T ----------------
template<int MODE>
__global__ __launch_bounds__(256) void gemm_k(
    const unsigned short* __restrict__ A, const unsigned short* __restrict__ B0,
    void* __restrict__ Cout, const float* __restrict__ resid,
    int M, int N, int K, int ldA, int ldB, int ldC)
{
  constexpr int BM = 128, BN = 128, BK = 64;
  __shared__ __align__(16) unsigned short As[BM * BK];
  __shared__ __align__(16) unsigned short Bs[BN * BK];
  int bm = blockIdx.x, bn = blockIdx.y;
  int t = threadIdx.x, w = t >> 6, l = t & 63, g = l >> 4, q = l & 15;
  int wm = w >> 1, wn = w & 1;

  const char* aSrc[4];
  const char* bSrc[4];
#pragma unroll
  for (int i = 0; i < 4; ++i) {
    int r = i * 32 + w * 8 + (l >> 3);
    aSrc[i] = (const char*)(A + (long)(bm * BM + r) * ldA) + (((l & 7) * 16) ^ ((r & 7) << 4));
    bSrc[i] = (const char*)(B0 + (long)(bn * BN + r) * ldB) + (((l & 7) * 16) ^ ((r & 7) << 4));
  }
  f32x4 acc[4][4];
#pragma unroll
  for (int mi = 0; mi < 4; ++mi)
#pragma unroll
    for (int ni = 0; ni < 4; ++ni) acc[mi][ni] = f32x4{0.f, 0.f, 0.f, 0.f};

  for (int k0 = 0; k0 < K; k0 += BK) {
#pragma unroll
    for (int i = 0; i < 4; ++i) {
      async16(aSrc[i] + (long)k0 * 2, &As[(i * 32 + w * 8) * BK]);
      async16(bSrc[i] + (long)k0 * 2, &Bs[(i * 32 + w * 8) * BK]);
    }
    asm volatile("s_waitcnt vmcnt(0)" ::: "memory");
    __syncthreads();
#pragma unroll
    for (int kk = 0; kk < 2; ++kk) {
      int col = (kk * 64 + g * 16) ^ ((q & 7) << 4);
      short8 af[4], bfm[4];
#pragma unroll
      for (int mi = 0; mi < 4; ++mi)
        af[mi] = *(const short8*)&As[(wm * 64 + mi * 16 + q) * BK + (col >> 1)];
#pragma unroll
      for (int ni = 0; ni < 4; ++ni)
        bfm[ni] = *(const short8*)&Bs[(wn * 64 + ni * 16 + q) * BK + (col >> 1)];
#pragma unroll
      for (int mi = 0; mi < 4; ++mi)
#pragma unroll
        for (int ni = 0; ni < 4; ++ni)
          acc[mi][ni] = mfma16(af[mi], bfm[ni], acc[mi][ni]);
    }
    __syncthreads();
  }
#pragma unroll
  for (int mi = 0; mi < 4; ++mi) {
#pragma unroll
    for (int r = 0; r < 4; ++r) {
      int grow = bm * BM + wm * 64 + mi * 16 + g * 4 + r;
#pragma unroll
      for (int ni = 0; ni < 4; ++ni) {
        int gcol = bn * BN + wn * 64 + ni * 16 + q;
        float v = acc[mi][ni][r];
        if (MODE == 0) {
          ((unsigned short*)Cout)[(long)grow * ldC + gcol] = f2bf(v);
        } else {
          long idx = (long)grow * ldC + gcol;
          ((float*)Cout)[idx] = resid[idx] + v;
        }
      }
    }
  }
}

// ------- persistent fused MoE up-proj (BN=64 dual-B, tb-outer/jj-inner) -------
__global__ __launch_bounds__(256, 3) void moe_up_k(
    const unsigned short* __restrict__ xn, const unsigned short* __restrict__ w1T,
    const unsigned short* __restrict__ w3T, unsigned short* __restrict__ hbuf,
    const int* __restrict__ lstAll, const int* __restrict__ cntAll)
{
  constexpr int BM = 128, BN = 64, BK = 64, NBN = FF / BN;   // 56
  constexpr int NJJ = NBN / 8;                                // 7
  __shared__ __align__(16) unsigned short As[BM * BK];
  __shared__ __align__(16) unsigned short Bs[2][BN * BK];
  int t = threadIdx.x, w = t >> 6, l = t & 63, g = l >> 4, q = l & 15;
  int wm = w >> 1, wn = w & 1;
  int xcd = blockIdx.x & 7, slot = blockIdx.x >> 3, SLOTS = gridDim.x >> 3;

  int TB = 0;
  for (int e = 0; e < NE; ++e) TB += (cntAll[e] + BM - 1) >> 7;

  for (int lidx = slot; lidx < TB * NJJ; lidx += SLOTS) {
    int tb = lidx / NJJ, jj = lidx - tb * NJJ;
    int bn = xcd + 8 * jj;
    int e = 0, base = 0, cnt = 0, bm = 0;
    for (; e < NE; ++e) {
      cnt = cntAll[e];
      int te = (cnt + BM - 1) >> 7;
      if (tb < te) { bm = tb; break; }
      tb -= te; base += cnt;
    }
    const int* lst = lstAll + e * NTOK;
    const unsigned short* B0 = w1T + (size_t)e * FF * DM + (size_t)bn * BN * DM;
    const unsigned short* B1 = w3T + (size_t)e * FF * DM + (size_t)bn * BN * DM;

    const char* aSrc[4];
    const char* b0Src[2];
    const char* b1Src[2];
#pragma unroll
    for (int i = 0; i < 4; ++i) {
      int r = i * 32 + w * 8 + (l >> 3);
      int grow = bm * BM + r;
      int arow = lst[grow < cnt ? grow : 0];
      int swz = ((l & 7) * 16) ^ ((r & 7) << 4);
      aSrc[i] = (const char*)(xn + (long)arow * DM) + swz;
      if (i < 2) {
        b0Src[i] = (const char*)(B0 + (long)r * DM) + swz;
        b1Src[i] = (const char*)(B1 + (long)r * DM) + swz;
      }
    }
    f32x4 acc0[4][2], acc1[4][2];
#pragma unroll
    for (int mi = 0; mi < 4; ++mi)
#pragma unroll
      for (int ni = 0; ni < 2; ++ni) {
        acc0[mi][ni] = f32x4{0.f, 0.f, 0.f, 0.f};
        acc1[mi][ni] = f32x4{0.f, 0.f, 0.f, 0.f};
      }

    for (int k0 = 0; k0 < DM; k0 += BK) {
#pragma unroll
      for (int i = 0; i < 4; ++i)
        async16(aSrc[i] + (long)k0 * 2, &As[(i * 32 + w * 8) * BK]);
#pragma unroll
      for (int i = 0; i < 2; ++i) {
        async16(b0Src[i] + (long)k0 * 2, &Bs[0][(i * 32 + w * 8) * BK]);
        async16(b1Src[i] + (long)k0 * 2, &Bs[1][(i * 32 + w * 8) * BK]);
      }
      asm volatile("s_waitcnt vmcnt(0)" ::: "memory");
      __syncthreads();
#pragma unroll
      for (int kk = 0; kk < 2; ++kk) {
        int col = (kk * 64 + g * 16) ^ ((q & 7) << 4);
        short8 af[4], bf0[2], bf1[2];
#pragma unroll
        for (int mi = 0; mi < 4; ++mi)
          af[mi] = *(const short8*)&As[(wm * 64 + mi * 16 + q) * BK + (col >> 1)];
#pragma unroll
        for (int ni = 0; ni < 2; ++ni) {
          int r = wn * 32 + ni * 16 + q;
          bf0[ni] = *(const short8*)&Bs[0][r * BK + (col >> 1)];
          bf1[ni] = *(const short8*)&Bs[1][r * BK + (col >> 1)];
        }
#pragma unroll
        for (int mi = 0; mi < 4; ++mi)
#pragma unroll
          for (int ni = 0; ni < 2; ++ni) {
            acc0[mi][ni] = mfma16(af[mi], bf0[ni], acc0[mi][ni]);
            acc1[mi][ni] = mfma16(af[mi], bf1[ni], acc1[mi][ni]);
          }
      }
      __syncthreads();
    }
#pragma unroll
    for (int mi = 0; mi < 4; ++mi) {
#pragma unroll
      for (int r = 0; r < 4; ++r) {
        int grow = bm * BM + wm * 64 + mi * 16 + g * 4 + r;
        if (grow >= cnt) continue;
        unsigned short* hp = hbuf + (size_t)(base + grow) * FF + bn * BN + wn * 32;
#pragma unroll
        for (int ni = 0; ni < 2; ++ni) {
          float v1 = acc0[mi][ni][r];
          float v3 = acc1[mi][ni][r];
          float sg = v1 / (1.0f + __expf(-v1));
          hp[ni * 16 + q] = f2bf(sg * v3);
        }
      }
    }
  }
}

// ------- persistent MoE down-proj (bn==XCD, BN=128) -------
__global__ __launch_bounds__(256, 3) void moe_dn_k(
    const unsigned short* __restrict__ hbuf, const unsigned short* __restrict__ w2T,
    unsigned short* __restrict__ ybuf, const int* __restrict__ cntAll)
{
  constexpr int BM = 128, BN = 128, BK = 64;
  __shared__ __align__(16) unsigned short As[BM * BK];
  __shared__ __align__(16) unsigned short Bs[BN * BK];
  int t = threadIdx.x, w = t >> 6, l = t & 63, g = l >> 4, q = l & 15;
  int wm = w >> 1, wn = w & 1;
  int xcd = blockIdx.x & 7, slot = blockIdx.x >> 3, SLOTS = gridDim.x >> 3;
  int bn = xcd;

  int TB = 0;
  for (int e = 0; e < NE; ++e) TB += (cntAll[e] + BM - 1) >> 7;

  for (int tb0 = slot; tb0 < TB; tb0 += SLOTS) {
    int tb = tb0;
    int e = 0, base = 0, cnt = 0, bm = 0;
    for (; e < NE; ++e) {
      cnt = cntAll[e];
      int te = (cnt + BM - 1) >> 7;
      if (tb < te) { bm = tb; break; }
      tb -= te; base += cnt;
    }
    const unsigned short* B0 = w2T + (size_t)e * DM * FF + (size_t)bn * BN * FF;

    const char* aSrc[4];
    const char* bSrc[4];
#pragma unroll
    for (int i = 0; i < 4; ++i) {
      int r = i * 32 + w * 8 + (l >> 3);
      int grow = bm * BM + r;
      int arow = base + (grow < cnt ? grow : 0);
      int swz = ((l & 7) * 16) ^ ((r & 7) << 4);
      aSrc[i] = (const char*)(hbuf + (long)arow * FF) + swz;
      bSrc[i] = (const char*)(B0 + (long)r * FF) + swz;
    }
    f32x4 acc[4][4];
#pragma unroll
    for (int mi = 0; mi < 4; ++mi)
#pragma unroll
      for (int ni = 0; ni < 4; ++ni) acc[mi][ni] = f32x4{0.f, 0.f, 0.f, 0.f};

    for (int k0 = 0; k0 < FF; k0 += BK) {
#pragma unroll
      for (int i = 0; i < 4; ++i) {
        async16(aSrc[i] + (long)k0 * 2, &As[(i * 32 + w * 8) * BK]);
        async16(bSrc[i] + (long)k0 * 2, &Bs[(i * 32 + w * 8) * BK]);
      }
      asm volatile("s_waitcnt vmcnt(0)" ::: "memory");
      __syncthreads();
#pragma unroll
      for (int kk = 0; kk < 2; ++kk) {
        int col = (kk * 64 + g * 16) ^ ((q & 7) << 4);
        short8 af[4], bfm[4];
#pragma unroll
        for (int mi = 0; mi < 4; ++mi)
          af[mi] = *(const short8*)&As[(wm * 64 + mi * 16 + q) * BK + (col >> 1)];
#pragma unroll
        for (int ni = 0; ni < 4; ++ni)
          bfm[ni] = *(const short8*)&Bs[(wn * 64 + ni * 16 + q) * BK + (col >> 1)];
#pragma unroll
        for (int mi = 0; mi < 4; ++mi)
#pragma unroll
          for (int ni = 0; ni < 4; ++ni)
            acc[mi][ni] = mfma16(af[mi], bfm[ni], acc[mi][ni]);
      }
      __syncthreads();
    }
#pragma unroll
    for (int mi = 0; mi < 4; ++mi) {
#pragma unroll
      for (int r = 0; r < 4; ++r) {
        int grow = bm * BM + wm * 64 + mi * 16 + g * 4 + r;
        if (grow >= cnt) continue;
        unsigned short* yp = ybuf + (size_t)(base + grow) * DM + bn * BN + wn * 64;
#pragma unroll
        for (int ni = 0; ni < 4; ++ni)
          yp[ni * 16 + q] = f2bf(acc[mi][ni][r]);
      }
    }
  }
}

// ---------------- final MoE gather (+ lb in block 0) ----------------
__global__ __launch_bounds__(256) void moe_gather_k(
    const unsigned short* __restrict__ ybuf, const int* __restrict__ tokslot,
    const float* __restrict__ wtop, const int* __restrict__ cntAll,
    const int* __restrict__ cnt0, const int* __restrict__ cnt1,
    const float* __restrict__ probsum, const float* __restrict__ lbin,
    float* __restrict__ out)
{
  __shared__ int base8[NE];
  int tok = blockIdx.x, t = threadIdx.x;
  if (t < NE) {
    int b = 0;
    for (int i = 0; i < t; ++i) b += cntAll[i];
    base8[t] = b;
  }
  __syncthreads();
  int s0 = tokslot[2 * tok], s1 = tokslot[2 * tok + 1];
  int slot0 = base8[s0 >> 16] + (s0 & 0xffff);
  int slot1 = base8[s1 >> 16] + (s1 & 0xffff);
  float w0 = wtop[2 * tok], w1 = wtop[2 * tok + 1];
  short4v a = *(const short4v*)(ybuf + (size_t)slot0 * DM + 4 * t);
  short4v b = *(const short4v*)(ybuf + (size_t)slot1 * DM + 4 * t);
  float4* op = (float4*)(out + (size_t)tok * DM);
  float4 o = op[t];
  o.x += w0 * bf2f((unsigned short)a[0]) + w1 * bf2f((unsigned short)b[0]);
  o.y += w0 * bf2f((unsigned short)a[1]) + w1 * bf2f((unsigned short)b[1]);
  o.z += w0 * bf2f((unsigned short)a[2]) + w1 * bf2f((unsigned short)b[2]);
  o.w += w0 * bf2f((unsigned short)a[3]) + w1 * bf2f((unsigned short)b[3]);
  op[t] = o;
  if (tok == 0 && t == 0) {
    float acc = 0.f;
    for (int e = 0; e < 8; ++e) acc += (float)(cnt0[e] + cnt1[e]) * probsum[e];
    out[(size_t)NTOK * DM] = lbin[0] + acc * (4.0f / ((float)NTOK * (float)NTOK));
  }
}

// ---------------- RoPE (Q,K in place) + V transpose, one dispatch ----------------
__global__ __launch_bounds__(256) void rope_vtrans_k(unsigned short* __restrict__ qkv,
                                                     const int* __restrict__ pos,
                                                     unsigned short* __restrict__ vt)
{
  if (blockIdx.x < NTOK) {
    int tok = blockIdx.x, t = threadIdx.x;
    __shared__ float cs[32], sn[32];
    if (t < 32) {
      float p = (float)pos[tok];
      float freq = __expf(-(float)t * 0.28782313663f);  // ln(10000)/32
      float a = p * freq;
      cs[t] = cosf(a); sn[t] = sinf(a);
    }
    __syncthreads();
    unsigned short* row = qkv + (long)tok * 2048;
#pragma unroll
    for (int idx = t; idx < 768; idx += 256) {
      int hh = idx >> 5, d = idx & 31;
      int col = (hh < 16) ? hh * 64 + d : 1024 + (hh - 16) * 64 + d;
      float x1 = bf2f(row[col]), x2 = bf2f(row[col + 32]);
      row[col]      = f2bf(x1 * cs[d] - x2 * sn[d]);
      row[col + 32] = f2bf(x2 * cs[d] + x1 * sn[d]);
    }
    return;
  }
  // V transpose: qkv V-section -> vt[b][kvh][d=64][S]
  __shared__ unsigned short tile[64][72];
  int lin = blockIdx.x - NTOK;                 // 0..511
  int s0 = (lin & 31) * 64, kvh = (lin >> 5) & 7, b = lin >> 8;
  int t = threadIdx.x;
  int tx4 = (t & 15) * 4, row = t >> 4;
  const unsigned short* src = qkv + (long)(b * SEQ + s0) * 2048 + 1536 + kvh * 64;
#pragma unroll
  for (int i = 0; i < 4; ++i) {
    int r = row + i * 16;
    *(short4v*)&tile[r][tx4] = *(const short4v*)(src + (long)r * 2048 + tx4);
  }
  __syncthreads();
  unsigned short* dst = vt + (long)((b * NKV + kvh) * 64) * SEQ + s0;
#pragma unroll
  for (int i = 0; i < 4; ++i) {
    int d = row + i * 16;
    union { unsigned short us[4]; short4v v; } o;
    o.us[0] = tile[tx4 + 0][d]; o.us[1] = tile[tx4 + 1][d];
    o.us[2] = tile[tx4 + 2][d]; o.us[3] = tile[tx4 + 3][d];
    *(short4v*)(dst + (long)d * SEQ + tx4) = o.v;
  }
}

// ---------------- causal GQA flash attention (512 thr: 2 heads of one KV group) --------
__global__ __launch_bounds__(512) void attn_k(const unsigned short* __restrict__ qkv,
                                              const unsigned short* __restrict__ vtg,
                                              unsigned short* __restrict__ aout)
{
  int b = blockIdx.z;
  int qt = b ? (31 - blockIdx.x) : blockIdx.x;
  int kvh = blockIdx.y;
  int t = threadIdx.x, w = t >> 6, l = t & 63, g = l >> 4, q = l & 15;
  int h = kvh * 2 + (w >> 2);
  int wl = w & 3;
  __shared__ __align__(16) unsigned short Ks[2][4096];
  __shared__ __align__(16) unsigned short Vs[2][4096];
  int tok0 = b * SEQ;
  int myq = qt * 64 + wl * 16 + q;
  const unsigned short* qp = qkv + (long)(tok0 + myq) * 2048 + h * 64;
  short8 qf0 = *(const short8*)(qp + g * 8);
  short8 qf1 = *(const short8*)(qp + 32 + g * 8);
  const unsigned short* vtb = vtg + (long)((b * NKV + kvh) * 64) * SEQ;
  f32x4 o[4];
#pragma unroll
  for (int nf = 0; nf < 4; ++nf) o[nf] = f32x4{0.f, 0.f, 0.f, 0.f};
  float m = -1e30f, ssum = 0.0f;
  int r8 = w * 8 + (l >> 3);
  int sswz = ((l & 7) * 16) ^ ((r8 & 7) << 4);

  auto stage = [&](int kt, int buf) {
    const char* ksrc = (const char*)(qkv + (long)(tok0 + kt * 64 + r8) * 2048 + 1024 + kvh * 64) + sswz;
    async16(ksrc, &Ks[buf][r8 * 64]);
    const char* vsrc = (const char*)(vtb + (long)r8 * SEQ + kt * 64) + sswz;
    async16(vsrc, &Vs[buf][r8 * 64]);
  };

  stage(0, 0);
  __syncthreads();
  int cur = 0;
  for (int kt = 0; kt <= qt; ++kt) {
    if (kt < qt) stage(kt + 1, cur ^ 1);
    f32x4 st[4];
#pragma unroll
    for (int mb = 0; mb < 4; ++mb) {
      int kr = mb * 16 + q;
      int c0 = (g * 16) ^ ((q & 7) << 4);
      int c1 = (64 + g * 16) ^ ((q & 7) << 4);
      short8 k0 = *(const short8*)&Ks[cur][kr * 64 + (c0 >> 1)];
      short8 k1 = *(const short8*)&Ks[cur][kr * 64 + (c1 >> 1)];
      f32x4 z = f32x4{0.f, 0.f, 0.f, 0.f};
      __builtin_amdgcn_s_setprio(1);
      z = mfma16(k0, qf0, z);
      z = mfma16(k1, qf1, z);
      __builtin_amdgcn_s_setprio(0);
      st[mb] = z;
    }
    float p[4][4];
    float tmax = -1e30f;
#pragma unroll
    for (int mb = 0; mb < 4; ++mb)
#pragma unroll
      for (int r = 0; r < 4; ++r) {
        float v = st[mb][r] * 0.125f;
        int kvg = kt * 64 + mb * 16 + g * 4 + r;
        if (kvg > myq) v = -1e30f;
        p[mb][r] = v;
        tmax = fmaxf(tmax, v);
      }
    tmax = fmaxf(tmax, __shfl_xor(tmax, 16));
    tmax = fmaxf(tmax, __shfl_xor(tmax, 32));
    float mnew = fmaxf(m, tmax);
    float fac = __expf(m - mnew);
    m = mnew;
    float ps = 0.0f;
#pragma unroll
    for (int mb = 0; mb < 4; ++mb)
#pragma unroll
      for (int r = 0; r < 4; ++r) { float e = __expf(p[mb][r] - m); p[mb][r] = e; ps += e; }
    ps += __shfl_xor(ps, 16);
    ps += __shfl_xor(ps, 32);
    ssum = ssum * fac + ps;
#pragma unroll
    for (int r = 0; r < 4; ++r) {
      float ff = __shfl(fac, g * 4 + r);
#pragma unroll
      for (int nf = 0; nf < 4; ++nf) o[nf][r] *= ff;
    }
    unsigned pw[4][2];
#pragma unroll
    for (int mb = 0; mb < 4; ++mb) {
      pw[mb][0] = ((unsigned)f2bf(p[mb][1]) << 16) | f2bf(p[mb][0]);
      pw[mb][1] = ((unsigned)f2bf(p[mb][3]) << 16) | f2bf(p[mb][2]);
    }
    short8 pa[2];
#pragma unroll
    for (int f = 0; f < 2; ++f) {
      union { unsigned u[4]; short8 s; } cv;
#pragma unroll
      for (int i = 0; i < 4; ++i) {
        int srcl = ((g & 1) * 2 + (i >> 1)) * 16 + q;
        unsigned aa = (unsigned)__shfl((int)pw[2 * f][i & 1], srcl);
        unsigned bb = (unsigned)__shfl((int)pw[2 * f + 1][i & 1], srcl);
        cv.u[i] = (g & 2) ? bb : aa;
      }
      pa[f] = cv.s;
    }
#pragma unroll
    for (int kk = 0; kk < 2; ++kk) {
      int cb = (kk * 64 + g * 16) ^ ((q & 7) << 4);
      __builtin_amdgcn_s_setprio(1);
#pragma unroll
      for (int nf = 0; nf < 4; ++nf) {
        short8 vb = *(const short8*)&Vs[cur][(nf * 16 + q) * 64 + (cb >> 1)];
        o[nf] = mfma16(pa[kk], vb, o[nf]);
      }
      __builtin_amdgcn_s_setprio(0);
    }
    __syncthreads();
    cur ^= 1;
  }
#pragma unroll
  for (int r = 0; r < 4; ++r) {
    float is = 1.0f / __shfl(ssum, g * 4 + r);
    int orow = tok0 + qt * 64 + wl * 16 + g * 4 + r;
    unsigned short* op = aout + (long)orow * 1024 + h * 64;
    op[q]      = f2bf(o[0][r] * is);
    op[16 + q] = f2bf(o[1][r] * is);
    op[32 + q] = f2bf(o[2][r] * is);
    op[48 + q] = f2bf(o[3][r] * is);
  }
}

// ---------------- rmsnorm2 + router (atomic-free) ----------------
__global__ __launch_bounds__(256) void router_k(
    const float* __restrict__ hid, const float* __restrict__ w2n, const float* __restrict__ Wg,
    unsigned short* __restrict__ xn, float* __restrict__ probs8,
    int* __restrict__ top0, int* __restrict__ top1, float* __restrict__ wtop)
{
  int row = blockIdx.x, t = threadIdx.x;
  const float4* xr = (const float4*)(hid + (long)row * DM);
  float4 v = xr[t];
  float ss = v.x * v.x + v.y * v.y + v.z * v.z + v.w * v.w;
#pragma unroll
  for (int o = 32; o; o >>= 1) ss += __shfl_xor(ss, o);
  __shared__ float red[4];
  __shared__ float lred[4][8];
  __shared__ float lg[8];
  if ((t & 63) == 0) red[t >> 6] = ss;
  __syncthreads();
  float tot = red[0] + red[1] + red[2] + red[3];
  float rms = rsqrtf(tot * (1.0f / DM) + 1e-5f);
  float4 wv = ((const float4*)w2n)[t];
  float x0 = v.x * rms * wv.x, x1 = v.y * rms * wv.y, x2 = v.z * rms * wv.z, x3 = v.w * rms * wv.w;
  union { unsigned short us[4]; short4v s; } o4;
  o4.us[0] = f2bf(x0); o4.us[1] = f2bf(x1); o4.us[2] = f2bf(x2); o4.us[3] = f2bf(x3);
  *(short4v*)(xn + (long)row * DM + 4 * t) = o4.s;
  const float* wgr = Wg + t * 32;
  float lacc[8];
#pragma unroll
  for (int e = 0; e < 8; ++e)
    lacc[e] = x0 * wgr[e] + x1 * wgr[8 + e] + x2 * wgr[16 + e] + x3 * wgr[24 + e];
#pragma unroll
  for (int e = 0; e < 8; ++e)
#pragma unroll
    for (int o = 32; o; o >>= 1) lacc[e] += __shfl_xor(lacc[e], o);
  if ((t & 63) == 0)
#pragma unroll
    for (int e = 0; e < 8; ++e) lred[t >> 6][e] = lacc[e];
  __syncthreads();
  if (t < 8) lg[t] = lred[0][t] + lred[1][t] + lred[2][t] + lred[3][t];
  __syncthreads();
  if (t == 0) {
    float p[8];
    float mx = lg[0];
#pragma unroll
    for (int e = 1; e < 8; ++e) mx = fmaxf(mx, lg[e]);
    float s = 0.f;
#pragma unroll
    for (int e = 0; e < 8; ++e) { p[e] = __expf(lg[e] - mx); s += p[e]; }
    float isv = 1.0f / s;
#pragma unroll
    for (int e = 0; e < 8; ++e) { p[e] *= isv; probs8[(long)row * 8 + e] = p[e]; }
    int i0 = 0;
#pragma unroll
    for (int e = 1; e < 8; ++e) if (p[e] > p[i0]) i0 = e;
    int i1 = (i0 == 0) ? 1 : 0;
#pragma unroll
    for (int e = 0; e < 8; ++e) if (e != i0 && p[e] > p[i1]) i1 = e;
    float sw = p[i0] + p[i1];
    top0[row] = i0; top1[row] = i1;
    wtop[2 * row] = p[i0] / sw; wtop[2 * row + 1] = p[i1] / sw;
  }
}

// ---------------- expert lists + gate-prob column sums (one dispatch, 16 blocks) -------
__global__ __launch_bounds__(256) void lists_lbsum_k(
    const int* __restrict__ top0, const int* __restrict__ top1,
    const float* __restrict__ wtop, const float* __restrict__ probs8,
    int* __restrict__ lst, int* __restrict__ tokslot,
    int* __restrict__ ecnt, int* __restrict__ cnt0, int* __restrict__ cnt1,
    float* __restrict__ probsum)
{
  int t = threadIdx.x, lane = t & 63, wv = t >> 6;
  if (blockIdx.x >= NE) {
    int e = blockIdx.x - NE;
    float s = 0.f;
    for (int tok = t; tok < NTOK; tok += 256) s += probs8[(long)tok * 8 + e];
#pragma unroll
    for (int o = 32; o; o >>= 1) s += __shfl_xor(s, o);
    __shared__ float r[4];
    if (lane == 0) r[wv] = s;
    __syncthreads();
    if (t == 0) probsum[e] = r[0] + r[1] + r[2] + r[3];
    return;
  }
  int e = blockIdx.x;
  __shared__ int wco[4];
  int base = 0, c0 = 0, c1 = 0;
  for (int t0 = 0; t0 < NTOK; t0 += 256) {
    int tok = t0 + t;
    int m0 = (top0[tok] == e), m1 = (top1[tok] == e);
    c0 += m0; c1 += m1;
    int matched = m0 | m1;
    unsigned long long mask = __ballot(matched);
    if (lane == 0) wco[wv] = __popcll(mask);
    __syncthreads();
    int off = base;
    for (int j = 0; j < wv; ++j) off += wco[j];
    int pos = off + __popcll(mask & ((1ull << lane) - 1ull));
    if (matched) {
      lst[e * NTOK + pos] = tok;
      tokslot[2 * tok + (m0 ? 0 : 1)] = (e << 16) | pos;
    }
    base += wco[0] + wco[1] + wco[2] + wco[3];
    __syncthreads();
  }
#pragma unroll
  for (int o = 32; o; o >>= 1) { c0 += __shfl_xor(c0, o); c1 += __shfl_xor(c1, o); }
  __shared__ int r0[4], r1[4];
  if (lane == 0) { r0[wv] = c0; r1[wv] = c1; }
  __syncthreads();
  if (t == 0) {
    ecnt[e] = base;
    cnt0[e] = r0[0] + r0[1] + r0[2] + r0[3];
    cnt1[e] = r1[0] + r1[1] + r1[2] + r1[3];
  }
}

extern "C" void kernel_launch(void* const* d_in, const int* in_sizes, int n_in,
                              void* d_out, int out_size, void* d_ws, size_t ws_size,
                              hipStream_t stream) {
  (void)in_sizes; (void)n_in; (void)out_size; (void)ws_size;
  const float* hid  = (const float*)d_in[0];
  const int*   pos  = (const int*)d_in[1];
  const float* lbin = (const float*)d_in[2];
  const float* ln1  = (const float*)d_in[3];
  const float* ln2  = (const float*)d_in[4];
  const float* Wq   = (const float*)d_in[5];
  const float* Wk   = (const float*)d_in[6];
  const float* Wv   = (const float*)d_in[7];
  const float* Wo   = (const float*)d_in[8];
  const float* Wg   = (const float*)d_in[9];
  const float* w1   = (const float*)d_in[10];
  const float* w2   = (const float*)d_in[11];
  const float* w3   = (const float*)d_in[12];
  float* out = (float*)d_out;

  char* ws = (char*)d_ws;
  size_t off = 0;
  auto alloc = [&](size_t bytes) { void* p = ws + off; off += (bytes + 255) & ~255ull; return p; };
  unsigned short* WqkvT = (unsigned short*)alloc(2048ull * 1024 * 2);
  unsigned short* WoT   = (unsigned short*)alloc(1024ull * 1024 * 2);
  unsigned short* w1T   = (unsigned short*)alloc((size_t)NE * FF * DM * 2);
  unsigned short* w3T   = (unsigned short*)alloc((size_t)NE * FF * DM * 2);
  unsigned short* w2T   = (unsigned short*)alloc((size_t)NE * DM * FF * 2);
  unsigned short* xn    = (unsigned short*)alloc((size_t)NTOK * DM * 2);
  unsigned short* vtg   = (unsigned short*)alloc((size_t)BATCH * NKV * 64 * SEQ * 2);
  unsigned short* ybuf  = (unsigned short*)alloc((size_t)(2 * NTOK) * DM * 2);
  int*   lst = (int*)alloc((size_t)NE * NTOK * 4);
  int*   tokslot = (int*)alloc((size_t)NTOK * 2 * 4);
  float* probs8 = (float*)alloc((size_t)NTOK * 8 * 4);
  int*   top0 = (int*)alloc((size_t)NTOK * 4);
  int*   top1 = (int*)alloc((size_t)NTOK * 4);
  float* wtop = (float*)alloc((size_t)NTOK * 2 * 4);
  int*   ctr = (int*)alloc(256);
  int*   ecnt = ctr;                    // [8]
  int*   cnt0 = ctr + 8;                // [8]
  int*   cnt1 = ctr + 16;               // [8]
  float* probsum = (float*)(ctr + 24);  // [8]
  size_t qkvB  = (size_t)NTOK * 2048 * 2;
  size_t aoutB = (size_t)NTOK * DM * 2;
  size_t hbufB = (size_t)(2 * NTOK + 128) * FF * 2;
  char* region = (char*)alloc(qkvB + aoutB > hbufB ? qkvB + aoutB : hbufB);
  unsigned short* qkv  = (unsigned short*)region;
  unsigned short* aout = (unsigned short*)(region + qkvB);
  unsigned short* hbuf = (unsigned short*)region;

  transpose_all_k<<<768 + 3 * 7168, 256, 0, stream>>>(Wq, Wk, Wv, Wo, w1, w2, w3,
                                                      WqkvT, WoT, w1T, w3T, w2T);
  rmsnorm_k<<<NTOK, 256, 0, stream>>>(hid, ln1, xn);
  gemm_k<0><<<dim3(32, 16), 256, 0, stream>>>(xn, WqkvT, qkv, nullptr,
                                              NTOK, 2048, 1024, 1024, 1024, 2048);
  rope_vtrans_k<<<NTOK + 512, 256, 0, stream>>>(qkv, pos, vtg);
  attn_k<<<dim3(SEQ / 64, NKV, BATCH), 512, 0, stream>>>(qkv, vtg, aout);
  gemm_k<1><<<dim3(32, 8), 256, 0, stream>>>(aout, WoT, d_out, hid,
                                             NTOK, 1024, 1024, 1024, 1024, 1024);
  router_k<<<NTOK, 256, 0, stream>>>(out, ln2, Wg, xn, probs8, top0, top1, wtop);
  lists_lbsum_k<<<16, 256, 0, stream>>>(top0, top1, wtop, probs8, lst, tokslot,
                                        ecnt, cnt0, cnt1, probsum);
  moe_up_k<<<768, 256, 0, stream>>>(xn, w1T, w3T, hbuf, lst, ecnt);
  moe_dn_k<<<768, 256, 0, stream>>>(hbuf, w2T, ybuf, ecnt);
  moe_gather_k<<<NTOK, 256, 0, stream>>>(ybuf, tokslot, wtop, ecnt,
                                         cnt0, cnt1, probsum, lbin, out);
}